// Round 9
// baseline (619.659 us; speedup 1.0000x reference)
//
#include <hip/hip_runtime.h>

#define C_DIM 64
#define B_DIM 4

typedef unsigned short u16;
typedef unsigned int u32;
typedef __attribute__((ext_vector_type(8))) short s16x8;
typedef __attribute__((ext_vector_type(4))) float f32x4;

__device__ __forceinline__ float bf2f(u16 v) {
    union { u32 u; float f; } t; t.u = ((u32)v) << 16; return t.f;
}
__device__ __forceinline__ u16 f2bf(float f) {
    union { u32 u; float f; } t; t.f = f;
    u32 u = t.u;
    return (u16)((u + 0x7FFF + ((u >> 16) & 1)) >> 16);  // RNE
}
__device__ __forceinline__ float lo16(u32 u) {
    union { u32 v; float f; } t; t.v = u << 16; return t.f;
}
__device__ __forceinline__ float hi16(u32 u) {
    union { u32 v; float f; } t; t.v = u & 0xffff0000u; return t.f;
}

// ---- fused: fp32 (B,N,C) -> bf16 (N,B*C) transpose+convert  AND  dst histogram ----
__global__ __launch_bounds__(256) void k_pre(
    const float* __restrict__ in, u16* __restrict__ outb, int n_nodes,
    const int* __restrict__ dst, int* __restrict__ counts, int n_edges,
    int cvt_blocks)
{
    if ((int)blockIdx.x < cvt_blocks) {
        int i = blockIdx.x * 256 + threadIdx.x;      // [0, n_nodes*32)
        if (i >= n_nodes * 32) return;
        int n = i >> 5;
        int r = i & 31;
        int b = r >> 3, c8 = (r & 7) << 3;
        const float4* p = (const float4*)(in + ((size_t)b * n_nodes + n) * 64 + c8);
        float4 A = p[0], B = p[1];
        ushort4 lo, hi;
        lo.x = f2bf(A.x); lo.y = f2bf(A.y); lo.z = f2bf(A.z); lo.w = f2bf(A.w);
        hi.x = f2bf(B.x); hi.y = f2bf(B.y); hi.z = f2bf(B.z); hi.w = f2bf(B.w);
        ushort4* q = (ushort4*)(outb + (size_t)n * 256 + b * 64 + c8);
        q[0] = lo; q[1] = hi;
    } else {
        int e = (blockIdx.x - cvt_blocks) * 256 + threadIdx.x;
        if (e < n_edges) atomicAdd(&counts[dst[e]], 1);
    }
}

// ---------------- CSR build ----------------

__global__ __launch_bounds__(256) void k_part(
    const int* __restrict__ counts, int* __restrict__ partials, int n_nodes)
{
    __shared__ int s[256];
    int i = blockIdx.x * 256 + threadIdx.x;
    int v = (i < n_nodes) ? counts[i] : 0;
    s[threadIdx.x] = v;
    __syncthreads();
    for (int d = 128; d > 0; d >>= 1) {
        if (threadIdx.x < d) s[threadIdx.x] += s[threadIdx.x + d];
        __syncthreads();
    }
    if (threadIdx.x == 0) partials[blockIdx.x] = s[0];
}

__global__ __launch_bounds__(256) void k_scan1(
    int* __restrict__ partials, int nb)
{
    __shared__ int s[256];
    int tid = threadIdx.x;
    int v = (tid < nb) ? partials[tid] : 0;
    s[tid] = v;
    __syncthreads();
    for (int d = 1; d < 256; d <<= 1) {
        int t = (tid >= d) ? s[tid - d] : 0;
        __syncthreads();
        s[tid] += t;
        __syncthreads();
    }
    if (tid < nb) partials[tid] = s[tid] - v;   // exclusive
}

__global__ __launch_bounds__(256) void k_final(
    const int* __restrict__ counts, const int* __restrict__ partials,
    int* __restrict__ offsets, int* __restrict__ cursor, int n_nodes)
{
    __shared__ int s[256];
    int tid = threadIdx.x;
    int i = blockIdx.x * 256 + tid;
    int v = (i < n_nodes) ? counts[i] : 0;
    s[tid] = v;
    __syncthreads();
    for (int d = 1; d < 256; d <<= 1) {
        int t = (tid >= d) ? s[tid - d] : 0;
        __syncthreads();
        s[tid] += t;
        __syncthreads();
    }
    if (i < n_nodes) {
        int off = partials[blockIdx.x] + s[tid] - v;
        offsets[i] = off;
        cursor[i] = off;
    }
}

__global__ __launch_bounds__(256) void k_fill(
    const int* __restrict__ src, const int* __restrict__ dst,
    int* __restrict__ cursor, u16* __restrict__ elist, int n_edges)
{
    int e = blockIdx.x * 256 + threadIdx.x;
    if (e < n_edges) {
        int pos = atomicAdd(&cursor[dst[e]], 1);
        elist[pos] = (u16)src[e];
    }
}

// ---- fused gather + MFMA mm with dynamic tile stealing ----
// hb: (N, B*C) bf16 == row-major (4N,64). One wave = one 16-row tile (4 nodes)
// grabbed from a global atomic counter (next grab prefetched under current
// tile's gather). Gather acc in regs -> private LDS slice (same-wave
// producer/consumer, no barriers) -> 8 MFMAs -> direct output write.
__global__ __launch_bounds__(256) void k_gmm(
    const u16* __restrict__ hb, const u16* __restrict__ elist,
    const int* __restrict__ offsets, int* __restrict__ ctr,
    const float* __restrict__ W, const float* __restrict__ bias,
    float* __restrict__ out_f32,       // (B,N,C) fp32, nullable
    u16* __restrict__ out_bf,          // (4N,64) bf16, nullable
    int n_nodes, int n_edges)
{
    __shared__ float lds[4][4][4][65];
    int wslot = threadIdx.x >> 6;
    int l = threadIdx.x & 63;
    int lr = l & 15;
    int lk = l >> 4;
    float* myl = &lds[wslot][0][0][0];

    // B fragments: lane needs W[t*16+lr][s*32+lk*8 ..+8]
    s16x8 bfrag[4][2];
#pragma unroll
    for (int t = 0; t < 4; ++t)
#pragma unroll
        for (int s = 0; s < 2; ++s) {
            const float* wp = W + (t * 16 + lr) * 64 + s * 32 + lk * 8;
            s16x8 f;
#pragma unroll
            for (int e = 0; e < 8; ++e) f[e] = (short)f2bf(wp[e]);
            bfrag[t][s] = f;
        }
    float bia[4];
#pragma unroll
    for (int t = 0; t < 4; ++t) bia[t] = bias[t * 16 + lr];

    const int NT = n_nodes >> 2;
    const u16* px = hb + (l << 2);                 // lane's 8B column slice
    int sbase = lk * 65 + (lr << 2);

    int tile;
    if (l == 0) tile = atomicAdd(ctr, 1);
    tile = __shfl(tile, 0);

    while (tile < NT) {
        int nxt;
        if (l == 0) nxt = atomicAdd(ctr, 1);       // prefetch next grab
        // ---- gather 4 nodes (register acc, 8-deep pipelined loads) ----
#pragma unroll 1
        for (int j = 0; j < 4; ++j) {
            int node = tile * 4 + j;
            int ks = __builtin_amdgcn_readfirstlane(offsets[node]);
            int ke = __builtin_amdgcn_readfirstlane(
                (node + 1 < n_nodes) ? offsets[node + 1] : n_edges);
            uint2 sv = *(const uint2*)(px + ((size_t)node << 8));   // self
            float a0 = lo16(sv.x), a1 = hi16(sv.x), a2 = lo16(sv.y), a3 = hi16(sv.y);
            int k = ks;
            for (; k + 8 <= ke; k += 8) {
                int s0 = elist[k + 0], s1 = elist[k + 1], s2 = elist[k + 2], s3 = elist[k + 3];
                int s4 = elist[k + 4], s5 = elist[k + 5], s6 = elist[k + 6], s7 = elist[k + 7];
                uint2 v0 = *(const uint2*)(px + ((size_t)s0 << 8));
                uint2 v1 = *(const uint2*)(px + ((size_t)s1 << 8));
                uint2 v2 = *(const uint2*)(px + ((size_t)s2 << 8));
                uint2 v3 = *(const uint2*)(px + ((size_t)s3 << 8));
                uint2 v4 = *(const uint2*)(px + ((size_t)s4 << 8));
                uint2 v5 = *(const uint2*)(px + ((size_t)s5 << 8));
                uint2 v6 = *(const uint2*)(px + ((size_t)s6 << 8));
                uint2 v7 = *(const uint2*)(px + ((size_t)s7 << 8));
                a0 += lo16(v0.x); a1 += hi16(v0.x); a2 += lo16(v0.y); a3 += hi16(v0.y);
                a0 += lo16(v1.x); a1 += hi16(v1.x); a2 += lo16(v1.y); a3 += hi16(v1.y);
                a0 += lo16(v2.x); a1 += hi16(v2.x); a2 += lo16(v2.y); a3 += hi16(v2.y);
                a0 += lo16(v3.x); a1 += hi16(v3.x); a2 += lo16(v3.y); a3 += hi16(v3.y);
                a0 += lo16(v4.x); a1 += hi16(v4.x); a2 += lo16(v4.y); a3 += hi16(v4.y);
                a0 += lo16(v5.x); a1 += hi16(v5.x); a2 += lo16(v5.y); a3 += hi16(v5.y);
                a0 += lo16(v6.x); a1 += hi16(v6.x); a2 += lo16(v6.y); a3 += hi16(v6.y);
                a0 += lo16(v7.x); a1 += hi16(v7.x); a2 += lo16(v7.y); a3 += hi16(v7.y);
            }
            for (; k < ke; ++k) {
                uint2 v = *(const uint2*)(px + ((size_t)elist[k] << 8));
                a0 += lo16(v.x); a1 += hi16(v.x); a2 += lo16(v.y); a3 += hi16(v.y);
            }
            int sb = j * 260 + sbase;
            myl[sb + 0] = a0; myl[sb + 1] = a1; myl[sb + 2] = a2; myl[sb + 3] = a3;
        }
        // ---- transpose read: A-frags for this 16-row tile ----
        int rb = (lr >> 2) * 260 + (lr & 3) * 65 + (lk << 3);
        s16x8 av0, av1;
#pragma unroll
        for (int e = 0; e < 8; ++e) {
            av0[e] = (short)f2bf(myl[rb + e]);
            av1[e] = (short)f2bf(myl[rb + 32 + e]);
        }
        // ---- 8 MFMAs ----
        f32x4 acc[4];
#pragma unroll
        for (int t = 0; t < 4; ++t)
            acc[t] = (f32x4){bia[t], bia[t], bia[t], bia[t]};
#pragma unroll
        for (int t = 0; t < 4; ++t) {
            acc[t] = __builtin_amdgcn_mfma_f32_16x16x32_bf16(av0, bfrag[t][0], acc[t], 0, 0, 0);
            acc[t] = __builtin_amdgcn_mfma_f32_16x16x32_bf16(av1, bfrag[t][1], acc[t], 0, 0, 0);
        }
        // ---- epilogue ----
        int row0 = tile * 16;
        if (out_bf) {
#pragma unroll
            for (int t = 0; t < 4; ++t)
#pragma unroll
                for (int reg = 0; reg < 4; ++reg) {
                    int r = row0 + lk * 4 + reg;
                    out_bf[(size_t)r * 64 + t * 16 + lr] = f2bf(acc[t][reg]);
                }
        }
        if (out_f32) {
#pragma unroll
            for (int t = 0; t < 4; ++t)
#pragma unroll
                for (int reg = 0; reg < 4; ++reg) {
                    int r = row0 + lk * 4 + reg;
                    int n = r >> 2, b = r & 3;
                    out_f32[(((size_t)b * n_nodes + n) << 6) + t * 16 + lr] = acc[t][reg];
                }
        }
        tile = __shfl(nxt, 0);
    }
}

// ---------------- fallback (atomic path, proven) ----------------

__global__ __launch_bounds__(256) void gin_scatter(
    const float* __restrict__ h, const int* __restrict__ src,
    const int* __restrict__ dst, float* __restrict__ agg,
    int n_edges, int n_nodes)
{
    long long i = (long long)blockIdx.x * blockDim.x + threadIdx.x;
    int e = (int)(i >> 6);
    if (e >= n_edges) return;
    int lane = (int)(i & 63);
    int b  = lane >> 4;
    int c4 = (lane & 15) << 2;
    int s = src[e];
    int d = dst[e];
    const float4 v = *reinterpret_cast<const float4*>(
        h + ((size_t)b * n_nodes + s) * C_DIM + c4);
    float* o = agg + ((size_t)b * n_nodes + d) * C_DIM + c4;
    unsafeAtomicAdd(o + 0, v.x);
    unsafeAtomicAdd(o + 1, v.y);
    unsafeAtomicAdd(o + 2, v.z);
    unsafeAtomicAdd(o + 3, v.w);
}

__global__ __launch_bounds__(256) void gin_mm(
    const float* __restrict__ hin, const float* __restrict__ agg,
    const float* __restrict__ W, const float* __restrict__ bias,
    float* __restrict__ out, int M)
{
    __shared__ float Ws[64][65];
    __shared__ float rows[4][64];
    int tid = threadIdx.x;
    for (int i = tid; i < 64 * 64; i += 256)
        Ws[i >> 6][i & 63] = W[i];
    int rloc = tid >> 6;
    int j    = tid & 63;
    int row  = blockIdx.x * 4 + rloc;
    if (row < M)
        rows[rloc][j] = hin[(size_t)row * C_DIM + j] + agg[(size_t)row * C_DIM + j];
    __syncthreads();
    if (row < M) {
        float acc = bias[j];
#pragma unroll
        for (int k = 0; k < 64; ++k)
            acc += rows[rloc][k] * Ws[j][k];
        out[(size_t)row * C_DIM + j] = acc;
    }
}

// ---------------- launch ----------------

static inline size_t align256(size_t x) { return (x + 255) & ~(size_t)255; }

extern "C" void kernel_launch(void* const* d_in, const int* in_sizes, int n_in,
                              void* d_out, int out_size, void* d_ws, size_t ws_size,
                              hipStream_t stream)
{
    const float* x   = (const float*)d_in[0];
    const int*   ei  = (const int*)d_in[1];
    const float* W1  = (const float*)d_in[2];
    const float* b1  = (const float*)d_in[3];
    const float* W2  = (const float*)d_in[4];
    const float* b2  = (const float*)d_in[5];
    float* out = (float*)d_out;

    const int n_nodes = in_sizes[0] / (B_DIM * C_DIM);
    const int n_edges = in_sizes[1] / 2;
    const int M = B_DIM * n_nodes;
    const size_t elems = (size_t)M * C_DIM;

    const int* src = ei;
    const int* dst = ei + n_edges;
    const int NB = (n_nodes + 255) / 256;

    const int GRID_GMM = 2048;       // full static residency; balance via stealing

    // ws layout (fast path)
    size_t off = 0;
    size_t o_bufA    = off; off = align256(off + elems * sizeof(u16));
    size_t o_bufB    = off; off = align256(off + elems * sizeof(u16));
    size_t o_counts  = off; off = align256(off + (size_t)n_nodes * sizeof(int));
    size_t o_offsets = off; off = align256(off + (size_t)n_nodes * sizeof(int));
    size_t o_cursor  = off; off = align256(off + (size_t)n_nodes * sizeof(int));
    size_t o_part    = off; off = align256(off + 256 * sizeof(int));
    size_t o_ctrs    = off; off = align256(off + 2 * sizeof(int));
    size_t o_elist   = off; off = align256(off + (size_t)n_edges * sizeof(u16));
    const size_t need = off;

    const bool fast = (ws_size >= need) && (n_nodes <= 65535) && (NB <= 256) &&
                      ((elems & 7) == 0) && ((n_nodes & 3) == 0);

    dim3 blk(256);

    if (fast) {
        char* ws = (char*)d_ws;
        u16* bufA    = (u16*)(ws + o_bufA);
        u16* bufB    = (u16*)(ws + o_bufB);
        int* counts  = (int*)(ws + o_counts);
        int* offsets = (int*)(ws + o_offsets);
        int* cursor  = (int*)(ws + o_cursor);
        int* partials= (int*)(ws + o_part);
        int* ctrs    = (int*)(ws + o_ctrs);
        u16* elist   = (u16*)(ws + o_elist);

        const int cvt_blocks  = (n_nodes * 32 + 255) / 256;
        const int hist_blocks = (n_edges + 255) / 256;
        dim3 grid_pre((unsigned)(cvt_blocks + hist_blocks));
        dim3 grid_e((unsigned)hist_blocks);
        dim3 grid_n((unsigned)NB);
        dim3 grid_g((unsigned)GRID_GMM);

        hipMemsetAsync(counts, 0, (size_t)n_nodes * sizeof(int), stream);
        hipMemsetAsync(ctrs, 0, 2 * sizeof(int), stream);
        k_pre<<<grid_pre, blk, 0, stream>>>(x, bufA, n_nodes, dst, counts,
                                            n_edges, cvt_blocks);
        k_part<<<grid_n, blk, 0, stream>>>(counts, partials, n_nodes);
        k_scan1<<<1, blk, 0, stream>>>(partials, NB);
        k_final<<<grid_n, blk, 0, stream>>>(counts, partials, offsets, cursor, n_nodes);
        k_fill<<<grid_e, blk, 0, stream>>>(src, dst, cursor, elist, n_edges);

        // layer 1: bf16 (N,BC) -> bf16 (N,BC)
        k_gmm<<<grid_g, blk, 0, stream>>>(bufA, elist, offsets, ctrs + 0, W1, b1,
                                          nullptr, bufB, n_nodes, n_edges);
        // layer 2: bf16 (N,BC) -> fp32 (B,N,C)
        k_gmm<<<grid_g, blk, 0, stream>>>(bufB, elist, offsets, ctrs + 1, W2, b2,
                                          out, nullptr, n_nodes, n_edges);
    } else {
        // fallback: atomic path
        float* agg = (float*)d_ws;
        const size_t h_bytes = elems * sizeof(float);
        dim3 grid_sc((unsigned)(((long long)n_edges * 64 + 255) / 256));
        dim3 grid_mm((unsigned)((M + 3) / 4));

        hipMemsetAsync(agg, 0, h_bytes, stream);
        gin_scatter<<<grid_sc, blk, 0, stream>>>(x, src, dst, agg, n_edges, n_nodes);
        gin_mm<<<grid_mm, blk, 0, stream>>>(x, agg, W1, b1, out, M);

        hipMemsetAsync(agg, 0, h_bytes, stream);
        gin_scatter<<<grid_sc, blk, 0, stream>>>(out, src, dst, agg, n_edges, n_nodes);
        gin_mm<<<grid_mm, blk, 0, stream>>>(out, agg, W2, b2, out, M);
    }
}

// Round 10
// 367.594 us; speedup vs baseline: 1.6857x; 1.6857x over previous
//
#include <hip/hip_runtime.h>

#define C_DIM 64
#define B_DIM 4

typedef unsigned short u16;
typedef unsigned int u32;
typedef __attribute__((ext_vector_type(8))) short s16x8;
typedef __attribute__((ext_vector_type(4))) float f32x4;

__device__ __forceinline__ u16 f2bf(float f) {
    union { u32 u; float f; } t; t.f = f;
    u32 u = t.u;
    return (u16)((u + 0x7FFF + ((u >> 16) & 1)) >> 16);  // RNE
}
__device__ __forceinline__ float lo16(u32 u) {
    union { u32 v; float f; } t; t.v = u << 16; return t.f;
}
__device__ __forceinline__ float hi16(u32 u) {
    union { u32 v; float f; } t; t.v = u & 0xffff0000u; return t.f;
}

// ---- fused: fp32 (B,N,C) -> bf16 (N,B*C) transpose+convert, dst histogram,
//      and zeroing of the sentinel row bufA[n_nodes] ----
__global__ __launch_bounds__(256) void k_pre(
    const float* __restrict__ in, u16* __restrict__ outb, int n_nodes,
    const int* __restrict__ dst, int* __restrict__ counts, int n_edges,
    int cvt_blocks, int hist_blocks)
{
    int bid = (int)blockIdx.x;
    if (bid < cvt_blocks) {
        int i = bid * 256 + threadIdx.x;             // [0, n_nodes*32)
        if (i >= n_nodes * 32) return;
        int n = i >> 5;
        int r = i & 31;
        int b = r >> 3, c8 = (r & 7) << 3;
        const float4* p = (const float4*)(in + ((size_t)b * n_nodes + n) * 64 + c8);
        float4 A = p[0], B = p[1];
        ushort4 lo, hi;
        lo.x = f2bf(A.x); lo.y = f2bf(A.y); lo.z = f2bf(A.z); lo.w = f2bf(A.w);
        hi.x = f2bf(B.x); hi.y = f2bf(B.y); hi.z = f2bf(B.z); hi.w = f2bf(B.w);
        ushort4* q = (ushort4*)(outb + (size_t)n * 256 + b * 64 + c8);
        q[0] = lo; q[1] = hi;
    } else if (bid < cvt_blocks + hist_blocks) {
        int e = (bid - cvt_blocks) * 256 + threadIdx.x;
        if (e < n_edges) atomicAdd(&counts[dst[e]], 1);
    } else {
        // zero the sentinel row (node index n_nodes): 256 u16
        outb[(size_t)n_nodes * 256 + threadIdx.x] = 0;
    }
}

// ---- single-block padded exclusive scan: offsets[i] = 8-aligned CSR start;
//      offsets[n_nodes] = total padded; cursor = offsets ----
__global__ __launch_bounds__(1024) void k_scanall(
    const int* __restrict__ counts, int* __restrict__ offsets,
    int* __restrict__ cursor, int n_nodes)
{
    __shared__ int s[1024];
    int tid = threadIdx.x;
    int chunk = (n_nodes + 1023) >> 10;
    int lo = tid * chunk;
    int hi = lo + chunk; if (hi > n_nodes) hi = n_nodes;
    int sum = 0;
    for (int i = lo; i < hi; ++i) sum += (counts[i] + 7) & ~7;
    s[tid] = sum;
    __syncthreads();
    for (int d = 1; d < 1024; d <<= 1) {
        int t = (tid >= d) ? s[tid - d] : 0;
        __syncthreads();
        s[tid] += t;
        __syncthreads();
    }
    int base = s[tid] - sum;   // exclusive prefix
    for (int i = lo; i < hi; ++i) {
        offsets[i] = base;
        cursor[i] = base;
        base += (counts[i] + 7) & ~7;
    }
    if (tid == 1023) offsets[n_nodes] = s[1023];
}

// ---- fused: elist fill (first fill_blocks) + sentinel padding (rest) ----
__global__ __launch_bounds__(256) void k_fillp(
    const int* __restrict__ src, const int* __restrict__ dst,
    int* __restrict__ cursor, u16* __restrict__ elist,
    const int* __restrict__ offsets, const int* __restrict__ counts,
    int n_nodes, int n_edges, int fill_blocks, int sentinel)
{
    if ((int)blockIdx.x < fill_blocks) {
        int e = blockIdx.x * 256 + threadIdx.x;
        if (e < n_edges) {
            int pos = atomicAdd(&cursor[dst[e]], 1);
            elist[pos] = (u16)src[e];
        }
    } else {
        int i = (blockIdx.x - fill_blocks) * 256 + threadIdx.x;
        if (i < n_nodes) {
            int e0 = offsets[i] + counts[i];
            int e1 = offsets[i + 1];
            for (int e = e0; e < e1; ++e) elist[e] = (u16)sentinel;
        }
    }
}

// ---- gather(+self): one wave per node, no LDS, no barriers ----
// hb/aggb: (N, B*C) bf16; lane l owns 8B at col l*4. Every CSR segment is a
// multiple of 8 and 8-aligned (16B-aligned uint4 index loads, no tails);
// sentinel edges read the zeroed row n_nodes (L1-hot, adds exact 0).
// asm keep-alive forces all 8 gathers simultaneously in flight; next batch's
// index uint4 is prefetched before the adds.
__global__ __launch_bounds__(256, 8) void k_gather(
    const u16* __restrict__ hb, const u16* __restrict__ elist,
    const int* __restrict__ offsets, u16* __restrict__ aggb,
    int n_nodes)
{
    int gw = (blockIdx.x * 256 + threadIdx.x) >> 6;
    int nw = (gridDim.x * 256) >> 6;
    int l = threadIdx.x & 63;
    const u16* px = hb + (l << 2);

    for (int node = gw; node < n_nodes; node += nw) {
        int ks = __builtin_amdgcn_readfirstlane(offsets[node]);
        int ke = __builtin_amdgcn_readfirstlane(offsets[node + 1]);
        uint2 sv = *(const uint2*)(px + ((size_t)node << 8));   // self
        float a0 = lo16(sv.x), a1 = hi16(sv.x), a2 = lo16(sv.y), a3 = hi16(sv.y);
        int nb = (ke - ks) >> 3;
        uint4 I = make_uint4(0u, 0u, 0u, 0u);
        if (nb > 0) I = *(const uint4*)(elist + ks);
        int k = ks;
        for (int b = 0; b < nb; ++b) {
            uint4 In = I;
            if (b + 1 < nb) In = *(const uint4*)(elist + k + 8);  // prefetch
            u32 s0 = I.x & 0xffffu, s1 = I.x >> 16;
            u32 s2 = I.y & 0xffffu, s3 = I.y >> 16;
            u32 s4 = I.z & 0xffffu, s5 = I.z >> 16;
            u32 s6 = I.w & 0xffffu, s7 = I.w >> 16;
            uint2 v0 = *(const uint2*)(px + ((size_t)s0 << 8));
            uint2 v1 = *(const uint2*)(px + ((size_t)s1 << 8));
            uint2 v2 = *(const uint2*)(px + ((size_t)s2 << 8));
            uint2 v3 = *(const uint2*)(px + ((size_t)s3 << 8));
            uint2 v4 = *(const uint2*)(px + ((size_t)s4 << 8));
            uint2 v5 = *(const uint2*)(px + ((size_t)s5 << 8));
            uint2 v6 = *(const uint2*)(px + ((size_t)s6 << 8));
            uint2 v7 = *(const uint2*)(px + ((size_t)s7 << 8));
            asm volatile("" ::
                "v"(v0.x), "v"(v0.y), "v"(v1.x), "v"(v1.y),
                "v"(v2.x), "v"(v2.y), "v"(v3.x), "v"(v3.y),
                "v"(v4.x), "v"(v4.y), "v"(v5.x), "v"(v5.y),
                "v"(v6.x), "v"(v6.y), "v"(v7.x), "v"(v7.y));
            a0 += lo16(v0.x); a1 += hi16(v0.x); a2 += lo16(v0.y); a3 += hi16(v0.y);
            a0 += lo16(v1.x); a1 += hi16(v1.x); a2 += lo16(v1.y); a3 += hi16(v1.y);
            a0 += lo16(v2.x); a1 += hi16(v2.x); a2 += lo16(v2.y); a3 += hi16(v2.y);
            a0 += lo16(v3.x); a1 += hi16(v3.x); a2 += lo16(v3.y); a3 += hi16(v3.y);
            a0 += lo16(v4.x); a1 += hi16(v4.x); a2 += lo16(v4.y); a3 += hi16(v4.y);
            a0 += lo16(v5.x); a1 += hi16(v5.x); a2 += lo16(v5.y); a3 += hi16(v5.y);
            a0 += lo16(v6.x); a1 += hi16(v6.x); a2 += lo16(v6.y); a3 += hi16(v6.y);
            a0 += lo16(v7.x); a1 += hi16(v7.x); a2 += lo16(v7.y); a3 += hi16(v7.y);
            I = In; k += 8;
        }
        uint2 o;
        o.x = (u32)f2bf(a0) | ((u32)f2bf(a1) << 16);
        o.y = (u32)f2bf(a2) | ((u32)f2bf(a3) << 16);
        *(uint2*)(aggb + ((size_t)node << 8) + (l << 2)) = o;
    }
}

// ---- MFMA matmul: D(R=4N,64) = A(R,64) @ W^T + bias (verified round 6) ----
__global__ __launch_bounds__(256) void k_mm_mfma(
    const u16* __restrict__ aggb,      // (4N, 64) bf16
    const float* __restrict__ W,       // (64,64) f32 row-major (out,in)
    const float* __restrict__ bias,
    float* __restrict__ out_f32,       // (B,N,C) fp32, nullable
    u16* __restrict__ out_bf,          // (4N,64) bf16, nullable
    int n_nodes)
{
    const int R = n_nodes * 4;
    int l = threadIdx.x & 63;
    int wid = (blockIdx.x * 256 + threadIdx.x) >> 6;
    int nwaves = (gridDim.x * 256) >> 6;
    int lr = l & 15;
    int lk = l >> 4;

    s16x8 bfrag[4][2];
#pragma unroll
    for (int t = 0; t < 4; ++t)
#pragma unroll
        for (int s = 0; s < 2; ++s) {
            const float* wp = W + (t * 16 + lr) * 64 + s * 32 + lk * 8;
            s16x8 f;
#pragma unroll
            for (int e = 0; e < 8; ++e) f[e] = (short)f2bf(wp[e]);
            bfrag[t][s] = f;
        }
    float bia[4];
#pragma unroll
    for (int t = 0; t < 4; ++t) bia[t] = bias[t * 16 + lr];

    for (int tile = wid; tile * 16 < R; tile += nwaves) {
        int row0 = tile * 16;
        const u16* ap = aggb + (size_t)(row0 + lr) * 64 + lk * 8;
        s16x8 a0 = *(const s16x8*)(ap);
        s16x8 a1 = *(const s16x8*)(ap + 32);
        f32x4 acc[4];
#pragma unroll
        for (int t = 0; t < 4; ++t)
            acc[t] = (f32x4){bia[t], bia[t], bia[t], bia[t]};
#pragma unroll
        for (int t = 0; t < 4; ++t) {
            acc[t] = __builtin_amdgcn_mfma_f32_16x16x32_bf16(a0, bfrag[t][0], acc[t], 0, 0, 0);
            acc[t] = __builtin_amdgcn_mfma_f32_16x16x32_bf16(a1, bfrag[t][1], acc[t], 0, 0, 0);
        }
        if (out_bf) {
#pragma unroll
            for (int t = 0; t < 4; ++t)
#pragma unroll
                for (int reg = 0; reg < 4; ++reg) {
                    int r = row0 + lk * 4 + reg;
                    out_bf[(size_t)r * 64 + t * 16 + lr] = f2bf(acc[t][reg]);
                }
        }
        if (out_f32) {
#pragma unroll
            for (int t = 0; t < 4; ++t)
#pragma unroll
                for (int reg = 0; reg < 4; ++reg) {
                    int r = row0 + lk * 4 + reg;
                    int n = r >> 2, b = r & 3;
                    out_f32[(((size_t)b * n_nodes + n) << 6) + t * 16 + lr] = acc[t][reg];
                }
        }
    }
}

// ---------------- fallback (atomic path, proven) ----------------

__global__ __launch_bounds__(256) void gin_scatter(
    const float* __restrict__ h, const int* __restrict__ src,
    const int* __restrict__ dst, float* __restrict__ agg,
    int n_edges, int n_nodes)
{
    long long i = (long long)blockIdx.x * blockDim.x + threadIdx.x;
    int e = (int)(i >> 6);
    if (e >= n_edges) return;
    int lane = (int)(i & 63);
    int b  = lane >> 4;
    int c4 = (lane & 15) << 2;
    int s = src[e];
    int d = dst[e];
    const float4 v = *reinterpret_cast<const float4*>(
        h + ((size_t)b * n_nodes + s) * C_DIM + c4);
    float* o = agg + ((size_t)b * n_nodes + d) * C_DIM + c4;
    unsafeAtomicAdd(o + 0, v.x);
    unsafeAtomicAdd(o + 1, v.y);
    unsafeAtomicAdd(o + 2, v.z);
    unsafeAtomicAdd(o + 3, v.w);
}

__global__ __launch_bounds__(256) void gin_mm(
    const float* __restrict__ hin, const float* __restrict__ agg,
    const float* __restrict__ W, const float* __restrict__ bias,
    float* __restrict__ out, int M)
{
    __shared__ float Ws[64][65];
    __shared__ float rows[4][64];
    int tid = threadIdx.x;
    for (int i = tid; i < 64 * 64; i += 256)
        Ws[i >> 6][i & 63] = W[i];
    int rloc = tid >> 6;
    int j    = tid & 63;
    int row  = blockIdx.x * 4 + rloc;
    if (row < M)
        rows[rloc][j] = hin[(size_t)row * C_DIM + j] + agg[(size_t)row * C_DIM + j];
    __syncthreads();
    if (row < M) {
        float acc = bias[j];
#pragma unroll
        for (int k = 0; k < 64; ++k)
            acc += rows[rloc][k] * Ws[j][k];
        out[(size_t)row * C_DIM + j] = acc;
    }
}

// ---------------- launch ----------------

static inline size_t align256(size_t x) { return (x + 255) & ~(size_t)255; }

extern "C" void kernel_launch(void* const* d_in, const int* in_sizes, int n_in,
                              void* d_out, int out_size, void* d_ws, size_t ws_size,
                              hipStream_t stream)
{
    const float* x   = (const float*)d_in[0];
    const int*   ei  = (const int*)d_in[1];
    const float* W1  = (const float*)d_in[2];
    const float* b1  = (const float*)d_in[3];
    const float* W2  = (const float*)d_in[4];
    const float* b2  = (const float*)d_in[5];
    float* out = (float*)d_out;

    const int n_nodes = in_sizes[0] / (B_DIM * C_DIM);
    const int n_edges = in_sizes[1] / 2;
    const int M = B_DIM * n_nodes;
    const size_t elems = (size_t)M * C_DIM;

    const int* src = ei;
    const int* dst = ei + n_edges;

    // elist capacity: every node padded up to +7 entries
    const size_t elist_cap = (size_t)n_edges + 8u * (size_t)n_nodes;

    // ws layout (fast path)
    size_t off = 0;
    size_t o_bufA    = off; off = align256(off + (elems + 256) * sizeof(u16)); // + sentinel row
    size_t o_bufB    = off; off = align256(off + elems * sizeof(u16));
    size_t o_counts  = off; off = align256(off + (size_t)n_nodes * sizeof(int));
    size_t o_offsets = off; off = align256(off + (size_t)(n_nodes + 1) * sizeof(int));
    size_t o_cursor  = off; off = align256(off + (size_t)n_nodes * sizeof(int));
    size_t o_elist   = off; off = align256(off + elist_cap * sizeof(u16));
    const size_t need = off;

    const bool fast = (ws_size >= need) && (n_nodes <= 65535) &&
                      ((elems & 7) == 0) && ((n_nodes & 3) == 0);

    dim3 blk(256);

    if (fast) {
        char* ws = (char*)d_ws;
        u16* bufA    = (u16*)(ws + o_bufA);
        u16* bufB    = (u16*)(ws + o_bufB);
        int* counts  = (int*)(ws + o_counts);
        int* offsets = (int*)(ws + o_offsets);
        int* cursor  = (int*)(ws + o_cursor);
        u16* elist   = (u16*)(ws + o_elist);

        const int cvt_blocks  = (n_nodes * 32 + 255) / 256;
        const int hist_blocks = (n_edges + 255) / 256;
        const int node_blocks = (n_nodes + 255) / 256;
        dim3 grid_pre((unsigned)(cvt_blocks + hist_blocks + 1));
        dim3 grid_fp((unsigned)(hist_blocks + node_blocks));
        dim3 grid_g(2048);
        dim3 grid_m(2048);

        hipMemsetAsync(counts, 0, (size_t)n_nodes * sizeof(int), stream);
        k_pre<<<grid_pre, blk, 0, stream>>>(x, bufA, n_nodes, dst, counts,
                                            n_edges, cvt_blocks, hist_blocks);
        k_scanall<<<1, dim3(1024), 0, stream>>>(counts, offsets, cursor, n_nodes);
        k_fillp<<<grid_fp, blk, 0, stream>>>(src, dst, cursor, elist, offsets,
                                             counts, n_nodes, n_edges,
                                             hist_blocks, n_nodes);

        // layer 1: bf16 (N,BC) -> agg -> h1 bf16 (overwrites bufA rows 0..R-1)
        k_gather<<<grid_g, blk, 0, stream>>>(bufA, elist, offsets, bufB, n_nodes);
        k_mm_mfma<<<grid_m, blk, 0, stream>>>(bufB, W1, b1, nullptr, bufA, n_nodes);
        // layer 2: h1 -> agg -> fp32 (B,N,C)
        k_gather<<<grid_g, blk, 0, stream>>>(bufA, elist, offsets, bufB, n_nodes);
        k_mm_mfma<<<grid_m, blk, 0, stream>>>(bufB, W2, b2, out, nullptr, n_nodes);
    } else {
        // fallback: atomic path
        float* agg = (float*)d_ws;
        const size_t h_bytes = elems * sizeof(float);
        dim3 grid_sc((unsigned)(((long long)n_edges * 64 + 255) / 256));
        dim3 grid_mm((unsigned)((M + 3) / 4));

        hipMemsetAsync(agg, 0, h_bytes, stream);
        gin_scatter<<<grid_sc, blk, 0, stream>>>(x, src, dst, agg, n_edges, n_nodes);
        gin_mm<<<grid_mm, blk, 0, stream>>>(x, agg, W1, b1, out, M);

        hipMemsetAsync(agg, 0, h_bytes, stream);
        gin_scatter<<<grid_sc, blk, 0, stream>>>(out, src, dst, agg, n_edges, n_nodes);
        gin_mm<<<grid_mm, blk, 0, stream>>>(out, agg, W2, b2, out, M);
    }
}

// Round 11
// 265.400 us; speedup vs baseline: 2.3348x; 1.3851x over previous
//
#include <hip/hip_runtime.h>

#define C_DIM 64
#define B_DIM 4

typedef unsigned short u16;
typedef unsigned int u32;
typedef __attribute__((ext_vector_type(8))) short s16x8;
typedef __attribute__((ext_vector_type(4))) float f32x4;

__device__ __forceinline__ u16 f2bf(float f) {
    union { u32 u; float f; } t; t.f = f;
    u32 u = t.u;
    return (u16)((u + 0x7FFF + ((u >> 16) & 1)) >> 16);  // RNE
}
__device__ __forceinline__ float lo16(u32 u) {
    union { u32 v; float f; } t; t.v = u << 16; return t.f;
}
__device__ __forceinline__ float hi16(u32 u) {
    union { u32 v; float f; } t; t.v = u & 0xffff0000u; return t.f;
}
__device__ __forceinline__ int pad8(int v) { return (v + 7) & ~7; }

// ---- fused: fp32 (B,N,C) -> bf16 (N,B*C) transpose+convert, dst histogram,
//      and zeroing of the sentinel row bufA[n_nodes] ----
__global__ __launch_bounds__(256) void k_pre(
    const float* __restrict__ in, u16* __restrict__ outb, int n_nodes,
    const int* __restrict__ dst, int* __restrict__ counts, int n_edges,
    int cvt_blocks, int hist_blocks)
{
    int bid = (int)blockIdx.x;
    if (bid < cvt_blocks) {
        int i = bid * 256 + threadIdx.x;             // [0, n_nodes*32)
        if (i >= n_nodes * 32) return;
        int n = i >> 5;
        int r = i & 31;
        int b = r >> 3, c8 = (r & 7) << 3;
        const float4* p = (const float4*)(in + ((size_t)b * n_nodes + n) * 64 + c8);
        float4 A = p[0], B = p[1];
        ushort4 lo, hi;
        lo.x = f2bf(A.x); lo.y = f2bf(A.y); lo.z = f2bf(A.z); lo.w = f2bf(A.w);
        hi.x = f2bf(B.x); hi.y = f2bf(B.y); hi.z = f2bf(B.z); hi.w = f2bf(B.w);
        ushort4* q = (ushort4*)(outb + (size_t)n * 256 + b * 64 + c8);
        q[0] = lo; q[1] = hi;
    } else if (bid < cvt_blocks + hist_blocks) {
        int e = (bid - cvt_blocks) * 256 + threadIdx.x;
        if (e < n_edges) atomicAdd(&counts[dst[e]], 1);
    } else {
        // zero the sentinel row (node index n_nodes): 256 u16
        outb[(size_t)n_nodes * 256 + threadIdx.x] = 0;
    }
}

// ---------------- padded CSR scan (multi-block, proven structure) ----------------

__global__ __launch_bounds__(256) void k_part(
    const int* __restrict__ counts, int* __restrict__ partials, int n_nodes)
{
    __shared__ int s[256];
    int i = blockIdx.x * 256 + threadIdx.x;
    int v = (i < n_nodes) ? pad8(counts[i]) : 0;
    s[threadIdx.x] = v;
    __syncthreads();
    for (int d = 128; d > 0; d >>= 1) {
        if (threadIdx.x < d) s[threadIdx.x] += s[threadIdx.x + d];
        __syncthreads();
    }
    if (threadIdx.x == 0) partials[blockIdx.x] = s[0];
}

__global__ __launch_bounds__(256) void k_scan1(
    int* __restrict__ partials, int nb)
{
    __shared__ int s[256];
    int tid = threadIdx.x;
    int v = (tid < nb) ? partials[tid] : 0;
    s[tid] = v;
    __syncthreads();
    for (int d = 1; d < 256; d <<= 1) {
        int t = (tid >= d) ? s[tid - d] : 0;
        __syncthreads();
        s[tid] += t;
        __syncthreads();
    }
    if (tid < nb) partials[tid] = s[tid] - v;   // exclusive
}

__global__ __launch_bounds__(256) void k_final(
    const int* __restrict__ counts, const int* __restrict__ partials,
    int* __restrict__ offsets, int* __restrict__ cursor, int n_nodes)
{
    __shared__ int s[256];
    int tid = threadIdx.x;
    int i = blockIdx.x * 256 + tid;
    int v = (i < n_nodes) ? pad8(counts[i]) : 0;
    s[tid] = v;
    __syncthreads();
    for (int d = 1; d < 256; d <<= 1) {
        int t = (tid >= d) ? s[tid - d] : 0;
        __syncthreads();
        s[tid] += t;
        __syncthreads();
    }
    if (i < n_nodes) {
        int off = partials[blockIdx.x] + s[tid] - v;
        offsets[i] = off;
        cursor[i] = off;
        if (i == n_nodes - 1) offsets[n_nodes] = off + v;   // padded total
    }
}

// ---- fused: elist fill (first fill_blocks) + sentinel padding (rest) ----
__global__ __launch_bounds__(256) void k_fillp(
    const int* __restrict__ src, const int* __restrict__ dst,
    int* __restrict__ cursor, u16* __restrict__ elist,
    const int* __restrict__ offsets, const int* __restrict__ counts,
    int n_nodes, int n_edges, int fill_blocks, int sentinel)
{
    if ((int)blockIdx.x < fill_blocks) {
        int e = blockIdx.x * 256 + threadIdx.x;
        if (e < n_edges) {
            int pos = atomicAdd(&cursor[dst[e]], 1);
            elist[pos] = (u16)src[e];
        }
    } else {
        int i = (blockIdx.x - fill_blocks) * 256 + threadIdx.x;
        if (i < n_nodes) {
            int e0 = offsets[i] + counts[i];
            int e1 = offsets[i + 1];
            for (int e = e0; e < e1; ++e) elist[e] = (u16)sentinel;
        }
    }
}

// ---- gather(+self): one wave per node, no LDS, no barriers ----
// hb/aggb: (N, B*C) bf16; lane l owns 8B at col l*4. Every CSR segment is a
// multiple of 8 and 8-aligned (16B-aligned uint4 index loads, no tails);
// sentinel edges read the zeroed row n_nodes (L1-hot, adds exact 0).
__global__ __launch_bounds__(256, 8) void k_gather(
    const u16* __restrict__ hb, const u16* __restrict__ elist,
    const int* __restrict__ offsets, u16* __restrict__ aggb,
    int n_nodes)
{
    int gw = (blockIdx.x * 256 + threadIdx.x) >> 6;
    int nw = (gridDim.x * 256) >> 6;
    int l = threadIdx.x & 63;
    const u16* px = hb + (l << 2);

    for (int node = gw; node < n_nodes; node += nw) {
        int ks = __builtin_amdgcn_readfirstlane(offsets[node]);
        int ke = __builtin_amdgcn_readfirstlane(offsets[node + 1]);
        uint2 sv = *(const uint2*)(px + ((size_t)node << 8));   // self
        float a0 = lo16(sv.x), a1 = hi16(sv.x), a2 = lo16(sv.y), a3 = hi16(sv.y);
        int nb = (ke - ks) >> 3;
        uint4 I = make_uint4(0u, 0u, 0u, 0u);
        if (nb > 0) I = *(const uint4*)(elist + ks);
        int k = ks;
        for (int b = 0; b < nb; ++b) {
            uint4 In = I;
            if (b + 1 < nb) In = *(const uint4*)(elist + k + 8);  // prefetch
            u32 s0 = I.x & 0xffffu, s1 = I.x >> 16;
            u32 s2 = I.y & 0xffffu, s3 = I.y >> 16;
            u32 s4 = I.z & 0xffffu, s5 = I.z >> 16;
            u32 s6 = I.w & 0xffffu, s7 = I.w >> 16;
            uint2 v0 = *(const uint2*)(px + ((size_t)s0 << 8));
            uint2 v1 = *(const uint2*)(px + ((size_t)s1 << 8));
            uint2 v2 = *(const uint2*)(px + ((size_t)s2 << 8));
            uint2 v3 = *(const uint2*)(px + ((size_t)s3 << 8));
            uint2 v4 = *(const uint2*)(px + ((size_t)s4 << 8));
            uint2 v5 = *(const uint2*)(px + ((size_t)s5 << 8));
            uint2 v6 = *(const uint2*)(px + ((size_t)s6 << 8));
            uint2 v7 = *(const uint2*)(px + ((size_t)s7 << 8));
            asm volatile("" ::
                "v"(v0.x), "v"(v0.y), "v"(v1.x), "v"(v1.y),
                "v"(v2.x), "v"(v2.y), "v"(v3.x), "v"(v3.y),
                "v"(v4.x), "v"(v4.y), "v"(v5.x), "v"(v5.y),
                "v"(v6.x), "v"(v6.y), "v"(v7.x), "v"(v7.y));
            a0 += lo16(v0.x); a1 += hi16(v0.x); a2 += lo16(v0.y); a3 += hi16(v0.y);
            a0 += lo16(v1.x); a1 += hi16(v1.x); a2 += lo16(v1.y); a3 += hi16(v1.y);
            a0 += lo16(v2.x); a1 += hi16(v2.x); a2 += lo16(v2.y); a3 += hi16(v2.y);
            a0 += lo16(v3.x); a1 += hi16(v3.x); a2 += lo16(v3.y); a3 += hi16(v3.y);
            a0 += lo16(v4.x); a1 += hi16(v4.x); a2 += lo16(v4.y); a3 += hi16(v4.y);
            a0 += lo16(v5.x); a1 += hi16(v5.x); a2 += lo16(v5.y); a3 += hi16(v5.y);
            a0 += lo16(v6.x); a1 += hi16(v6.x); a2 += lo16(v6.y); a3 += hi16(v6.y);
            a0 += lo16(v7.x); a1 += hi16(v7.x); a2 += lo16(v7.y); a3 += hi16(v7.y);
            I = In; k += 8;
        }
        uint2 o;
        o.x = (u32)f2bf(a0) | ((u32)f2bf(a1) << 16);
        o.y = (u32)f2bf(a2) | ((u32)f2bf(a3) << 16);
        *(uint2*)(aggb + ((size_t)node << 8) + (l << 2)) = o;
    }
}

// ---- MFMA matmul: D(R=4N,64) = A(R,64) @ W^T + bias (verified round 6) ----
__global__ __launch_bounds__(256) void k_mm_mfma(
    const u16* __restrict__ aggb,      // (4N, 64) bf16
    const float* __restrict__ W,       // (64,64) f32 row-major (out,in)
    const float* __restrict__ bias,
    float* __restrict__ out_f32,       // (B,N,C) fp32, nullable
    u16* __restrict__ out_bf,          // (4N,64) bf16, nullable
    int n_nodes)
{
    const int R = n_nodes * 4;
    int l = threadIdx.x & 63;
    int wid = (blockIdx.x * 256 + threadIdx.x) >> 6;
    int nwaves = (gridDim.x * 256) >> 6;
    int lr = l & 15;
    int lk = l >> 4;

    s16x8 bfrag[4][2];
#pragma unroll
    for (int t = 0; t < 4; ++t)
#pragma unroll
        for (int s = 0; s < 2; ++s) {
            const float* wp = W + (t * 16 + lr) * 64 + s * 32 + lk * 8;
            s16x8 f;
#pragma unroll
            for (int e = 0; e < 8; ++e) f[e] = (short)f2bf(wp[e]);
            bfrag[t][s] = f;
        }
    float bia[4];
#pragma unroll
    for (int t = 0; t < 4; ++t) bia[t] = bias[t * 16 + lr];

    for (int tile = wid; tile * 16 < R; tile += nwaves) {
        int row0 = tile * 16;
        const u16* ap = aggb + (size_t)(row0 + lr) * 64 + lk * 8;
        s16x8 a0 = *(const s16x8*)(ap);
        s16x8 a1 = *(const s16x8*)(ap + 32);
        f32x4 acc[4];
#pragma unroll
        for (int t = 0; t < 4; ++t)
            acc[t] = (f32x4){bia[t], bia[t], bia[t], bia[t]};
#pragma unroll
        for (int t = 0; t < 4; ++t) {
            acc[t] = __builtin_amdgcn_mfma_f32_16x16x32_bf16(a0, bfrag[t][0], acc[t], 0, 0, 0);
            acc[t] = __builtin_amdgcn_mfma_f32_16x16x32_bf16(a1, bfrag[t][1], acc[t], 0, 0, 0);
        }
        if (out_bf) {
#pragma unroll
            for (int t = 0; t < 4; ++t)
#pragma unroll
                for (int reg = 0; reg < 4; ++reg) {
                    int r = row0 + lk * 4 + reg;
                    out_bf[(size_t)r * 64 + t * 16 + lr] = f2bf(acc[t][reg]);
                }
        }
        if (out_f32) {
#pragma unroll
            for (int t = 0; t < 4; ++t)
#pragma unroll
                for (int reg = 0; reg < 4; ++reg) {
                    int r = row0 + lk * 4 + reg;
                    int n = r >> 2, b = r & 3;
                    out_f32[(((size_t)b * n_nodes + n) << 6) + t * 16 + lr] = acc[t][reg];
                }
        }
    }
}

// ---------------- fallback (atomic path, proven) ----------------

__global__ __launch_bounds__(256) void gin_scatter(
    const float* __restrict__ h, const int* __restrict__ src,
    const int* __restrict__ dst, float* __restrict__ agg,
    int n_edges, int n_nodes)
{
    long long i = (long long)blockIdx.x * blockDim.x + threadIdx.x;
    int e = (int)(i >> 6);
    if (e >= n_edges) return;
    int lane = (int)(i & 63);
    int b  = lane >> 4;
    int c4 = (lane & 15) << 2;
    int s = src[e];
    int d = dst[e];
    const float4 v = *reinterpret_cast<const float4*>(
        h + ((size_t)b * n_nodes + s) * C_DIM + c4);
    float* o = agg + ((size_t)b * n_nodes + d) * C_DIM + c4;
    unsafeAtomicAdd(o + 0, v.x);
    unsafeAtomicAdd(o + 1, v.y);
    unsafeAtomicAdd(o + 2, v.z);
    unsafeAtomicAdd(o + 3, v.w);
}

__global__ __launch_bounds__(256) void gin_mm(
    const float* __restrict__ hin, const float* __restrict__ agg,
    const float* __restrict__ W, const float* __restrict__ bias,
    float* __restrict__ out, int M)
{
    __shared__ float Ws[64][65];
    __shared__ float rows[4][64];
    int tid = threadIdx.x;
    for (int i = tid; i < 64 * 64; i += 256)
        Ws[i >> 6][i & 63] = W[i];
    int rloc = tid >> 6;
    int j    = tid & 63;
    int row  = blockIdx.x * 4 + rloc;
    if (row < M)
        rows[rloc][j] = hin[(size_t)row * C_DIM + j] + agg[(size_t)row * C_DIM + j];
    __syncthreads();
    if (row < M) {
        float acc = bias[j];
#pragma unroll
        for (int k = 0; k < 64; ++k)
            acc += rows[rloc][k] * Ws[j][k];
        out[(size_t)row * C_DIM + j] = acc;
    }
}

// ---------------- launch ----------------

static inline size_t align256(size_t x) { return (x + 255) & ~(size_t)255; }

extern "C" void kernel_launch(void* const* d_in, const int* in_sizes, int n_in,
                              void* d_out, int out_size, void* d_ws, size_t ws_size,
                              hipStream_t stream)
{
    const float* x   = (const float*)d_in[0];
    const int*   ei  = (const int*)d_in[1];
    const float* W1  = (const float*)d_in[2];
    const float* b1  = (const float*)d_in[3];
    const float* W2  = (const float*)d_in[4];
    const float* b2  = (const float*)d_in[5];
    float* out = (float*)d_out;

    const int n_nodes = in_sizes[0] / (B_DIM * C_DIM);
    const int n_edges = in_sizes[1] / 2;
    const int M = B_DIM * n_nodes;
    const size_t elems = (size_t)M * C_DIM;

    const int* src = ei;
    const int* dst = ei + n_edges;
    const int NB = (n_nodes + 255) / 256;

    // elist capacity: every node padded up to +7 entries
    const size_t elist_cap = (size_t)n_edges + 8u * (size_t)n_nodes;

    // ws layout (fast path)
    size_t off = 0;
    size_t o_bufA    = off; off = align256(off + (elems + 256) * sizeof(u16)); // + sentinel row
    size_t o_bufB    = off; off = align256(off + elems * sizeof(u16));
    size_t o_counts  = off; off = align256(off + (size_t)n_nodes * sizeof(int));
    size_t o_offsets = off; off = align256(off + (size_t)(n_nodes + 1) * sizeof(int));
    size_t o_cursor  = off; off = align256(off + (size_t)n_nodes * sizeof(int));
    size_t o_part    = off; off = align256(off + 256 * sizeof(int));
    size_t o_elist   = off; off = align256(off + elist_cap * sizeof(u16));
    const size_t need = off;

    const bool fast = (ws_size >= need) && (n_nodes <= 65535) && (NB <= 256) &&
                      ((elems & 7) == 0) && ((n_nodes & 3) == 0);

    dim3 blk(256);

    if (fast) {
        char* ws = (char*)d_ws;
        u16* bufA    = (u16*)(ws + o_bufA);
        u16* bufB    = (u16*)(ws + o_bufB);
        int* counts  = (int*)(ws + o_counts);
        int* offsets = (int*)(ws + o_offsets);
        int* cursor  = (int*)(ws + o_cursor);
        int* partials= (int*)(ws + o_part);
        u16* elist   = (u16*)(ws + o_elist);

        const int cvt_blocks  = (n_nodes * 32 + 255) / 256;
        const int hist_blocks = (n_edges + 255) / 256;
        const int node_blocks = (n_nodes + 255) / 256;
        dim3 grid_pre((unsigned)(cvt_blocks + hist_blocks + 1));
        dim3 grid_n((unsigned)NB);
        dim3 grid_fp((unsigned)(hist_blocks + node_blocks));
        dim3 grid_g(2048);
        dim3 grid_m(2048);

        hipMemsetAsync(counts, 0, (size_t)n_nodes * sizeof(int), stream);
        k_pre<<<grid_pre, blk, 0, stream>>>(x, bufA, n_nodes, dst, counts,
                                            n_edges, cvt_blocks, hist_blocks);
        k_part<<<grid_n, blk, 0, stream>>>(counts, partials, n_nodes);
        k_scan1<<<1, blk, 0, stream>>>(partials, NB);
        k_final<<<grid_n, blk, 0, stream>>>(counts, partials, offsets, cursor, n_nodes);
        k_fillp<<<grid_fp, blk, 0, stream>>>(src, dst, cursor, elist, offsets,
                                             counts, n_nodes, n_edges,
                                             hist_blocks, n_nodes);

        // layer 1: bf16 (N,BC) -> agg -> h1 bf16 (overwrites bufA rows 0..R-1)
        k_gather<<<grid_g, blk, 0, stream>>>(bufA, elist, offsets, bufB, n_nodes);
        k_mm_mfma<<<grid_m, blk, 0, stream>>>(bufB, W1, b1, nullptr, bufA, n_nodes);
        // layer 2: h1 -> agg -> fp32 (B,N,C)
        k_gather<<<grid_g, blk, 0, stream>>>(bufA, elist, offsets, bufB, n_nodes);
        k_mm_mfma<<<grid_m, blk, 0, stream>>>(bufB, W2, b2, out, nullptr, n_nodes);
    } else {
        // fallback: atomic path
        float* agg = (float*)d_ws;
        const size_t h_bytes = elems * sizeof(float);
        dim3 grid_sc((unsigned)(((long long)n_edges * 64 + 255) / 256));
        dim3 grid_mm((unsigned)((M + 3) / 4));

        hipMemsetAsync(agg, 0, h_bytes, stream);
        gin_scatter<<<grid_sc, blk, 0, stream>>>(x, src, dst, agg, n_edges, n_nodes);
        gin_mm<<<grid_mm, blk, 0, stream>>>(x, agg, W1, b1, out, M);

        hipMemsetAsync(agg, 0, h_bytes, stream);
        gin_scatter<<<grid_sc, blk, 0, stream>>>(out, src, dst, agg, n_edges, n_nodes);
        gin_mm<<<grid_mm, blk, 0, stream>>>(out, agg, W2, b2, out, M);
    }
}

// Round 12
// 257.737 us; speedup vs baseline: 2.4042x; 1.0297x over previous
//
#include <hip/hip_runtime.h>

#define C_DIM 64
#define B_DIM 4

typedef unsigned short u16;
typedef unsigned int u32;
typedef __attribute__((ext_vector_type(8))) short s16x8;
typedef __attribute__((ext_vector_type(4))) float f32x4;

__device__ __forceinline__ u16 f2bf(float f) {
    union { u32 u; float f; } t; t.f = f;
    u32 u = t.u;
    return (u16)((u + 0x7FFF + ((u >> 16) & 1)) >> 16);  // RNE
}
__device__ __forceinline__ float lo16(u32 u) {
    union { u32 v; float f; } t; t.v = u << 16; return t.f;
}
__device__ __forceinline__ float hi16(u32 u) {
    union { u32 v; float f; } t; t.v = u & 0xffff0000u; return t.f;
}
__device__ __forceinline__ int pad8(int v) { return (v + 7) & ~7; }

// ---- fused: fp32 (B,N,C) -> bf16 (N,B*C) transpose+convert, dst histogram,
//      and zeroing of the sentinel row bufA[n_nodes] ----
__global__ __launch_bounds__(256) void k_pre(
    const float* __restrict__ in, u16* __restrict__ outb, int n_nodes,
    const int* __restrict__ dst, int* __restrict__ counts, int n_edges,
    int cvt_blocks, int hist_blocks)
{
    int bid = (int)blockIdx.x;
    if (bid < cvt_blocks) {
        int i = bid * 256 + threadIdx.x;             // [0, n_nodes*32)
        if (i >= n_nodes * 32) return;
        int n = i >> 5;
        int r = i & 31;
        int b = r >> 3, c8 = (r & 7) << 3;
        const float4* p = (const float4*)(in + ((size_t)b * n_nodes + n) * 64 + c8);
        float4 A = p[0], B = p[1];
        ushort4 lo, hi;
        lo.x = f2bf(A.x); lo.y = f2bf(A.y); lo.z = f2bf(A.z); lo.w = f2bf(A.w);
        hi.x = f2bf(B.x); hi.y = f2bf(B.y); hi.z = f2bf(B.z); hi.w = f2bf(B.w);
        ushort4* q = (ushort4*)(outb + (size_t)n * 256 + b * 64 + c8);
        q[0] = lo; q[1] = hi;
    } else if (bid < cvt_blocks + hist_blocks) {
        int e = (bid - cvt_blocks) * 256 + threadIdx.x;
        if (e < n_edges) atomicAdd(&counts[dst[e]], 1);
    } else {
        // zero the sentinel row (node index n_nodes): 256 u16
        outb[(size_t)n_nodes * 256 + threadIdx.x] = 0;
    }
}

// ---------------- padded CSR scan (multi-block, proven structure) ----------------

__global__ __launch_bounds__(256) void k_part(
    const int* __restrict__ counts, int* __restrict__ partials, int n_nodes)
{
    __shared__ int s[256];
    int i = blockIdx.x * 256 + threadIdx.x;
    int v = (i < n_nodes) ? pad8(counts[i]) : 0;
    s[threadIdx.x] = v;
    __syncthreads();
    for (int d = 128; d > 0; d >>= 1) {
        if (threadIdx.x < d) s[threadIdx.x] += s[threadIdx.x + d];
        __syncthreads();
    }
    if (threadIdx.x == 0) partials[blockIdx.x] = s[0];
}

__global__ __launch_bounds__(256) void k_scan1(
    int* __restrict__ partials, int nb)
{
    __shared__ int s[256];
    int tid = threadIdx.x;
    int v = (tid < nb) ? partials[tid] : 0;
    s[tid] = v;
    __syncthreads();
    for (int d = 1; d < 256; d <<= 1) {
        int t = (tid >= d) ? s[tid - d] : 0;
        __syncthreads();
        s[tid] += t;
        __syncthreads();
    }
    if (tid < nb) partials[tid] = s[tid] - v;   // exclusive
}

__global__ __launch_bounds__(256) void k_final(
    const int* __restrict__ counts, const int* __restrict__ partials,
    int* __restrict__ offsets, int* __restrict__ cursor, int n_nodes)
{
    __shared__ int s[256];
    int tid = threadIdx.x;
    int i = blockIdx.x * 256 + tid;
    int v = (i < n_nodes) ? pad8(counts[i]) : 0;
    s[tid] = v;
    __syncthreads();
    for (int d = 1; d < 256; d <<= 1) {
        int t = (tid >= d) ? s[tid - d] : 0;
        __syncthreads();
        s[tid] += t;
        __syncthreads();
    }
    if (i < n_nodes) {
        int off = partials[blockIdx.x] + s[tid] - v;
        offsets[i] = off;
        cursor[i] = off;
        if (i == n_nodes - 1) offsets[n_nodes] = off + v;   // padded total
    }
}

// ---- fused: elist fill (first fill_blocks) + sentinel padding (rest) ----
__global__ __launch_bounds__(256) void k_fillp(
    const int* __restrict__ src, const int* __restrict__ dst,
    int* __restrict__ cursor, u16* __restrict__ elist,
    const int* __restrict__ offsets, const int* __restrict__ counts,
    int n_nodes, int n_edges, int fill_blocks, int sentinel)
{
    if ((int)blockIdx.x < fill_blocks) {
        int e = blockIdx.x * 256 + threadIdx.x;
        if (e < n_edges) {
            int pos = atomicAdd(&cursor[dst[e]], 1);
            elist[pos] = (u16)src[e];
        }
    } else {
        int i = (blockIdx.x - fill_blocks) * 256 + threadIdx.x;
        if (i < n_nodes) {
            int e0 = offsets[i] + counts[i];
            int e1 = offsets[i + 1];
            for (int e = e0; e < e1; ++e) elist[e] = (u16)sentinel;
        }
    }
}

// ---- gather(+self), batch-half split: one wave = (node, batch-half h) ----
// hb/aggb: (N, B*C) bf16. Wave handles the 256B half-row [h*128 .. h*128+127]
// u16 cols; lane l owns 4B (2 bf16). h = blockIdx&1, so with round-robin
// block->XCD dispatch each XCD touches only one half => 12.8MB L2 working set.
// CSR segments are 8-padded (uint4 index loads, no tails); sentinel = zeroed row.
__global__ __launch_bounds__(256, 8) void k_gather(
    const u16* __restrict__ hb, const u16* __restrict__ elist,
    const int* __restrict__ offsets, u16* __restrict__ aggb,
    int n_nodes)
{
    int wslot = threadIdx.x >> 6;
    int l = threadIdx.x & 63;
    int h = blockIdx.x & 1;                          // batch-half (XCD parity)
    int idx = ((blockIdx.x >> 1) << 2) | wslot;      // wave index within half
    int nwh = (gridDim.x >> 1) << 2;                 // waves per half
    const u16* px = hb + (h << 7) + (l << 1);        // half-slice lane base (4B)

    for (int node = idx; node < n_nodes; node += nwh) {
        int ks = __builtin_amdgcn_readfirstlane(offsets[node]);
        int ke = __builtin_amdgcn_readfirstlane(offsets[node + 1]);
        u32 sv = *(const u32*)(px + ((size_t)node << 8));   // self (2 bf16)
        float a0 = lo16(sv), a1 = hi16(sv);
        int nb = (ke - ks) >> 3;
        uint4 I = make_uint4(0u, 0u, 0u, 0u);
        if (nb > 0) I = *(const uint4*)(elist + ks);
        int k = ks;
        for (int b = 0; b < nb; ++b) {
            uint4 In = I;
            if (b + 1 < nb) In = *(const uint4*)(elist + k + 8);  // prefetch
            u32 s0 = I.x & 0xffffu, s1 = I.x >> 16;
            u32 s2 = I.y & 0xffffu, s3 = I.y >> 16;
            u32 s4 = I.z & 0xffffu, s5 = I.z >> 16;
            u32 s6 = I.w & 0xffffu, s7 = I.w >> 16;
            u32 v0 = *(const u32*)(px + ((size_t)s0 << 8));
            u32 v1 = *(const u32*)(px + ((size_t)s1 << 8));
            u32 v2 = *(const u32*)(px + ((size_t)s2 << 8));
            u32 v3 = *(const u32*)(px + ((size_t)s3 << 8));
            u32 v4 = *(const u32*)(px + ((size_t)s4 << 8));
            u32 v5 = *(const u32*)(px + ((size_t)s5 << 8));
            u32 v6 = *(const u32*)(px + ((size_t)s6 << 8));
            u32 v7 = *(const u32*)(px + ((size_t)s7 << 8));
            asm volatile("" ::
                "v"(v0), "v"(v1), "v"(v2), "v"(v3),
                "v"(v4), "v"(v5), "v"(v6), "v"(v7));
            a0 += lo16(v0); a1 += hi16(v0);
            a0 += lo16(v1); a1 += hi16(v1);
            a0 += lo16(v2); a1 += hi16(v2);
            a0 += lo16(v3); a1 += hi16(v3);
            a0 += lo16(v4); a1 += hi16(v4);
            a0 += lo16(v5); a1 += hi16(v5);
            a0 += lo16(v6); a1 += hi16(v6);
            a0 += lo16(v7); a1 += hi16(v7);
            I = In; k += 8;
        }
        *(u32*)(aggb + ((size_t)node << 8) + (h << 7) + (l << 1)) =
            (u32)f2bf(a0) | ((u32)f2bf(a1) << 16);
    }
}

// ---- MFMA matmul: D(R=4N,64) = A(R,64) @ W^T + bias (verified round 6) ----
__global__ __launch_bounds__(256) void k_mm_mfma(
    const u16* __restrict__ aggb,      // (4N, 64) bf16
    const float* __restrict__ W,       // (64,64) f32 row-major (out,in)
    const float* __restrict__ bias,
    float* __restrict__ out_f32,       // (B,N,C) fp32, nullable
    u16* __restrict__ out_bf,          // (4N,64) bf16, nullable
    int n_nodes)
{
    const int R = n_nodes * 4;
    int l = threadIdx.x & 63;
    int wid = (blockIdx.x * 256 + threadIdx.x) >> 6;
    int nwaves = (gridDim.x * 256) >> 6;
    int lr = l & 15;
    int lk = l >> 4;

    s16x8 bfrag[4][2];
#pragma unroll
    for (int t = 0; t < 4; ++t)
#pragma unroll
        for (int s = 0; s < 2; ++s) {
            const float* wp = W + (t * 16 + lr) * 64 + s * 32 + lk * 8;
            s16x8 f;
#pragma unroll
            for (int e = 0; e < 8; ++e) f[e] = (short)f2bf(wp[e]);
            bfrag[t][s] = f;
        }
    float bia[4];
#pragma unroll
    for (int t = 0; t < 4; ++t) bia[t] = bias[t * 16 + lr];

    for (int tile = wid; tile * 16 < R; tile += nwaves) {
        int row0 = tile * 16;
        const u16* ap = aggb + (size_t)(row0 + lr) * 64 + lk * 8;
        s16x8 a0 = *(const s16x8*)(ap);
        s16x8 a1 = *(const s16x8*)(ap + 32);
        f32x4 acc[4];
#pragma unroll
        for (int t = 0; t < 4; ++t)
            acc[t] = (f32x4){bia[t], bia[t], bia[t], bia[t]};
#pragma unroll
        for (int t = 0; t < 4; ++t) {
            acc[t] = __builtin_amdgcn_mfma_f32_16x16x32_bf16(a0, bfrag[t][0], acc[t], 0, 0, 0);
            acc[t] = __builtin_amdgcn_mfma_f32_16x16x32_bf16(a1, bfrag[t][1], acc[t], 0, 0, 0);
        }
        if (out_bf) {
#pragma unroll
            for (int t = 0; t < 4; ++t)
#pragma unroll
                for (int reg = 0; reg < 4; ++reg) {
                    int r = row0 + lk * 4 + reg;
                    out_bf[(size_t)r * 64 + t * 16 + lr] = f2bf(acc[t][reg]);
                }
        }
        if (out_f32) {
#pragma unroll
            for (int t = 0; t < 4; ++t)
#pragma unroll
                for (int reg = 0; reg < 4; ++reg) {
                    int r = row0 + lk * 4 + reg;
                    int n = r >> 2, b = r & 3;
                    out_f32[(((size_t)b * n_nodes + n) << 6) + t * 16 + lr] = acc[t][reg];
                }
        }
    }
}

// ---------------- fallback (atomic path, proven) ----------------

__global__ __launch_bounds__(256) void gin_scatter(
    const float* __restrict__ h, const int* __restrict__ src,
    const int* __restrict__ dst, float* __restrict__ agg,
    int n_edges, int n_nodes)
{
    long long i = (long long)blockIdx.x * blockDim.x + threadIdx.x;
    int e = (int)(i >> 6);
    if (e >= n_edges) return;
    int lane = (int)(i & 63);
    int b  = lane >> 4;
    int c4 = (lane & 15) << 2;
    int s = src[e];
    int d = dst[e];
    const float4 v = *reinterpret_cast<const float4*>(
        h + ((size_t)b * n_nodes + s) * C_DIM + c4);
    float* o = agg + ((size_t)b * n_nodes + d) * C_DIM + c4;
    unsafeAtomicAdd(o + 0, v.x);
    unsafeAtomicAdd(o + 1, v.y);
    unsafeAtomicAdd(o + 2, v.z);
    unsafeAtomicAdd(o + 3, v.w);
}

__global__ __launch_bounds__(256) void gin_mm(
    const float* __restrict__ hin, const float* __restrict__ agg,
    const float* __restrict__ W, const float* __restrict__ bias,
    float* __restrict__ out, int M)
{
    __shared__ float Ws[64][65];
    __shared__ float rows[4][64];
    int tid = threadIdx.x;
    for (int i = tid; i < 64 * 64; i += 256)
        Ws[i >> 6][i & 63] = W[i];
    int rloc = tid >> 6;
    int j    = tid & 63;
    int row  = blockIdx.x * 4 + rloc;
    if (row < M)
        rows[rloc][j] = hin[(size_t)row * C_DIM + j] + agg[(size_t)row * C_DIM + j];
    __syncthreads();
    if (row < M) {
        float acc = bias[j];
#pragma unroll
        for (int k = 0; k < 64; ++k)
            acc += rows[rloc][k] * Ws[j][k];
        out[(size_t)row * C_DIM + j] = acc;
    }
}

// ---------------- launch ----------------

static inline size_t align256(size_t x) { return (x + 255) & ~(size_t)255; }

extern "C" void kernel_launch(void* const* d_in, const int* in_sizes, int n_in,
                              void* d_out, int out_size, void* d_ws, size_t ws_size,
                              hipStream_t stream)
{
    const float* x   = (const float*)d_in[0];
    const int*   ei  = (const int*)d_in[1];
    const float* W1  = (const float*)d_in[2];
    const float* b1  = (const float*)d_in[3];
    const float* W2  = (const float*)d_in[4];
    const float* b2  = (const float*)d_in[5];
    float* out = (float*)d_out;

    const int n_nodes = in_sizes[0] / (B_DIM * C_DIM);
    const int n_edges = in_sizes[1] / 2;
    const int M = B_DIM * n_nodes;
    const size_t elems = (size_t)M * C_DIM;

    const int* src = ei;
    const int* dst = ei + n_edges;
    const int NB = (n_nodes + 255) / 256;

    // elist capacity: every node padded up to +7 entries
    const size_t elist_cap = (size_t)n_edges + 8u * (size_t)n_nodes;

    // ws layout (fast path)
    size_t off = 0;
    size_t o_bufA    = off; off = align256(off + (elems + 256) * sizeof(u16)); // + sentinel row
    size_t o_bufB    = off; off = align256(off + elems * sizeof(u16));
    size_t o_counts  = off; off = align256(off + (size_t)n_nodes * sizeof(int));
    size_t o_offsets = off; off = align256(off + (size_t)(n_nodes + 1) * sizeof(int));
    size_t o_cursor  = off; off = align256(off + (size_t)n_nodes * sizeof(int));
    size_t o_part    = off; off = align256(off + 256 * sizeof(int));
    size_t o_elist   = off; off = align256(off + elist_cap * sizeof(u16));
    const size_t need = off;

    const bool fast = (ws_size >= need) && (n_nodes <= 65535) && (NB <= 256) &&
                      ((elems & 7) == 0) && ((n_nodes & 3) == 0);

    dim3 blk(256);

    if (fast) {
        char* ws = (char*)d_ws;
        u16* bufA    = (u16*)(ws + o_bufA);
        u16* bufB    = (u16*)(ws + o_bufB);
        int* counts  = (int*)(ws + o_counts);
        int* offsets = (int*)(ws + o_offsets);
        int* cursor  = (int*)(ws + o_cursor);
        int* partials= (int*)(ws + o_part);
        u16* elist   = (u16*)(ws + o_elist);

        const int cvt_blocks  = (n_nodes * 32 + 255) / 256;
        const int hist_blocks = (n_edges + 255) / 256;
        const int node_blocks = (n_nodes + 255) / 256;
        dim3 grid_pre((unsigned)(cvt_blocks + hist_blocks + 1));
        dim3 grid_n((unsigned)NB);
        dim3 grid_fp((unsigned)(hist_blocks + node_blocks));
        dim3 grid_g(2048);
        dim3 grid_m(2048);

        hipMemsetAsync(counts, 0, (size_t)n_nodes * sizeof(int), stream);
        k_pre<<<grid_pre, blk, 0, stream>>>(x, bufA, n_nodes, dst, counts,
                                            n_edges, cvt_blocks, hist_blocks);
        k_part<<<grid_n, blk, 0, stream>>>(counts, partials, n_nodes);
        k_scan1<<<1, blk, 0, stream>>>(partials, NB);
        k_final<<<grid_n, blk, 0, stream>>>(counts, partials, offsets, cursor, n_nodes);
        k_fillp<<<grid_fp, blk, 0, stream>>>(src, dst, cursor, elist, offsets,
                                             counts, n_nodes, n_edges,
                                             hist_blocks, n_nodes);

        // layer 1: bf16 (N,BC) -> agg -> h1 bf16 (overwrites bufA rows 0..R-1)
        k_gather<<<grid_g, blk, 0, stream>>>(bufA, elist, offsets, bufB, n_nodes);
        k_mm_mfma<<<grid_m, blk, 0, stream>>>(bufB, W1, b1, nullptr, bufA, n_nodes);
        // layer 2: h1 -> agg -> fp32 (B,N,C)
        k_gather<<<grid_g, blk, 0, stream>>>(bufA, elist, offsets, bufB, n_nodes);
        k_mm_mfma<<<grid_m, blk, 0, stream>>>(bufB, W2, b2, out, nullptr, n_nodes);
    } else {
        // fallback: atomic path
        float* agg = (float*)d_ws;
        const size_t h_bytes = elems * sizeof(float);
        dim3 grid_sc((unsigned)(((long long)n_edges * 64 + 255) / 256));
        dim3 grid_mm((unsigned)((M + 3) / 4));

        hipMemsetAsync(agg, 0, h_bytes, stream);
        gin_scatter<<<grid_sc, blk, 0, stream>>>(x, src, dst, agg, n_edges, n_nodes);
        gin_mm<<<grid_mm, blk, 0, stream>>>(x, agg, W1, b1, out, M);

        hipMemsetAsync(agg, 0, h_bytes, stream);
        gin_scatter<<<grid_sc, blk, 0, stream>>>(out, src, dst, agg, n_edges, n_nodes);
        gin_mm<<<grid_mm, blk, 0, stream>>>(out, agg, W2, b2, out, M);
    }
}

// Round 13
// 214.476 us; speedup vs baseline: 2.8892x; 1.2017x over previous
//
#include <hip/hip_runtime.h>

#define C_DIM 64
#define B_DIM 4

typedef unsigned short u16;
typedef unsigned int u32;
typedef __attribute__((ext_vector_type(8))) short s16x8;
typedef __attribute__((ext_vector_type(4))) float f32x4;

__device__ __forceinline__ u16 f2bf(float f) {
    union { u32 u; float f; } t; t.f = f;
    u32 u = t.u;
    return (u16)((u + 0x7FFF + ((u >> 16) & 1)) >> 16);  // RNE
}
__device__ __forceinline__ float lo16(u32 u) {
    union { u32 v; float f; } t; t.v = u << 16; return t.f;
}
__device__ __forceinline__ float hi16(u32 u) {
    union { u32 v; float f; } t; t.v = u & 0xffff0000u; return t.f;
}
__device__ __forceinline__ int pad8(int v) { return (v + 7) & ~7; }

// ---- fused: fp32 (B,N,C) -> bf16 (N,B*C) transpose+convert, dst histogram,
//      and zeroing of the sentinel rows of BOTH staging buffers ----
__global__ __launch_bounds__(256) void k_pre(
    const float* __restrict__ in, u16* __restrict__ outb, u16* __restrict__ outb2,
    int n_nodes, const int* __restrict__ dst, int* __restrict__ counts,
    int n_edges, int cvt_blocks, int hist_blocks)
{
    int bid = (int)blockIdx.x;
    if (bid < cvt_blocks) {
        int i = bid * 256 + threadIdx.x;             // [0, n_nodes*32)
        if (i >= n_nodes * 32) return;
        int n = i >> 5;
        int r = i & 31;
        int b = r >> 3, c8 = (r & 7) << 3;
        const float4* p = (const float4*)(in + ((size_t)b * n_nodes + n) * 64 + c8);
        float4 A = p[0], B = p[1];
        ushort4 lo, hi;
        lo.x = f2bf(A.x); lo.y = f2bf(A.y); lo.z = f2bf(A.z); lo.w = f2bf(A.w);
        hi.x = f2bf(B.x); hi.y = f2bf(B.y); hi.z = f2bf(B.z); hi.w = f2bf(B.w);
        ushort4* q = (ushort4*)(outb + (size_t)n * 256 + b * 64 + c8);
        q[0] = lo; q[1] = hi;
    } else if (bid < cvt_blocks + hist_blocks) {
        int e = (bid - cvt_blocks) * 256 + threadIdx.x;
        if (e < n_edges) atomicAdd(&counts[dst[e]], 1);
    } else {
        // zero sentinel rows (node index n_nodes) of both buffers
        outb [(size_t)n_nodes * 256 + threadIdx.x] = 0;
        outb2[(size_t)n_nodes * 256 + threadIdx.x] = 0;
    }
}

// ---------------- padded CSR scan (multi-block, proven) ----------------

__global__ __launch_bounds__(256) void k_part(
    const int* __restrict__ counts, int* __restrict__ partials, int n_nodes)
{
    __shared__ int s[256];
    int i = blockIdx.x * 256 + threadIdx.x;
    int v = (i < n_nodes) ? pad8(counts[i]) : 0;
    s[threadIdx.x] = v;
    __syncthreads();
    for (int d = 128; d > 0; d >>= 1) {
        if (threadIdx.x < d) s[threadIdx.x] += s[threadIdx.x + d];
        __syncthreads();
    }
    if (threadIdx.x == 0) partials[blockIdx.x] = s[0];
}

__global__ __launch_bounds__(256) void k_scan1(
    int* __restrict__ partials, int nb)
{
    __shared__ int s[256];
    int tid = threadIdx.x;
    int v = (tid < nb) ? partials[tid] : 0;
    s[tid] = v;
    __syncthreads();
    for (int d = 1; d < 256; d <<= 1) {
        int t = (tid >= d) ? s[tid - d] : 0;
        __syncthreads();
        s[tid] += t;
        __syncthreads();
    }
    if (tid < nb) partials[tid] = s[tid] - v;   // exclusive
}

__global__ __launch_bounds__(256) void k_final(
    const int* __restrict__ counts, const int* __restrict__ partials,
    int* __restrict__ offsets, int* __restrict__ cursor, int n_nodes)
{
    __shared__ int s[256];
    int tid = threadIdx.x;
    int i = blockIdx.x * 256 + tid;
    int v = (i < n_nodes) ? pad8(counts[i]) : 0;
    s[tid] = v;
    __syncthreads();
    for (int d = 1; d < 256; d <<= 1) {
        int t = (tid >= d) ? s[tid - d] : 0;
        __syncthreads();
        s[tid] += t;
        __syncthreads();
    }
    if (i < n_nodes) {
        int off = partials[blockIdx.x] + s[tid] - v;
        offsets[i] = off;
        cursor[i] = off;
        if (i == n_nodes - 1) offsets[n_nodes] = off + v;   // padded total
    }
}

// ---- fused: elist fill (first fill_blocks) + sentinel padding (rest) ----
__global__ __launch_bounds__(256) void k_fillp(
    const int* __restrict__ src, const int* __restrict__ dst,
    int* __restrict__ cursor, u16* __restrict__ elist,
    const int* __restrict__ offsets, const int* __restrict__ counts,
    int n_nodes, int n_edges, int fill_blocks, int sentinel)
{
    if ((int)blockIdx.x < fill_blocks) {
        int e = blockIdx.x * 256 + threadIdx.x;
        if (e < n_edges) {
            int pos = atomicAdd(&cursor[dst[e]], 1);
            elist[pos] = (u16)src[e];
        }
    } else {
        int i = (blockIdx.x - fill_blocks) * 256 + threadIdx.x;
        if (i < n_nodes) {
            int e0 = offsets[i] + counts[i];
            int e1 = offsets[i + 1];
            for (int e = e0; e < e1; ++e) elist[e] = (u16)sentinel;
        }
    }
}

// ---- fused half-split gather + cooperative MFMA matmul ----
// Block (tile tl, half h=blockIdx&1): wave w gathers node tl*4+w's h-half
// (batches 2h,2h+1; lane owns 4B = 2 bf16 — identical access pattern to the
// round-12 k_gather, XCD parity preserved). Packed bf16 agg lands in a tiny
// double-buffered LDS A-tile; after one barrier each wave runs its j-tile's
// two 16x16x32 MFMAs (invalid rows stay zero => contribute 0) and writes its
// 2 valid output rows. No agg round-trip, no separate mm kernel.
__global__ __launch_bounds__(256, 8) void k_gmm2(
    const u16* __restrict__ hb, const u16* __restrict__ elist,
    const int* __restrict__ offsets,
    const float* __restrict__ W,       // (64,64) f32 row-major (out,in)
    const float* __restrict__ bias,
    float* __restrict__ out_f32,       // (B,N,C) fp32, nullable
    u16* __restrict__ out_bf,          // (4N,64) bf16, nullable
    int n_nodes)
{
    __shared__ __align__(16) u32 lds[2][16][36];   // [buf][row][packed bf16x2]
    u32* lf = &lds[0][0][0];
    int tid = threadIdx.x;
    int w  = tid >> 6;            // wave = gathered node j AND mfma j-tile
    int l  = tid & 63;
    int lr = l & 15, lk = l >> 4;
    int h  = blockIdx.x & 1;      // batch-half (XCD parity)

    // zero-init LDS once: rows not owned by this block stay 0 forever
    for (int i = tid; i < 2 * 16 * 36; i += 256) lf[i] = 0u;

    // B fragments + bias for j-tile w only
    s16x8 bf0, bf1;
    {
        const float* wp = W + (w * 16 + lr) * 64 + lk * 8;
        s16x8 f0, f1;
#pragma unroll
        for (int e = 0; e < 8; ++e) {
            f0[e] = (short)f2bf(wp[e]);
            f1[e] = (short)f2bf(wp[e + 32]);
        }
        bf0 = f0; bf1 = f1;
    }
    float bia = bias[w * 16 + lr];

    const int NT = n_nodes >> 2;
    const u16* px = hb + (h << 7) + (l << 1);       // half-slice lane base
    int wword = (((w << 2) | (h << 1) | (l >> 5)) * 36) + (l & 31);
    int rsel = h << 1;                               // valid regs: 2h, 2h+1

    __syncthreads();                                 // LDS zero-init visible

    int buf = 0;
    int step = gridDim.x >> 1;
    for (int tl = blockIdx.x >> 1; tl < NT; tl += step, buf ^= 1) {
        int node = tl * 4 + w;
        // ---- gather this node's h-half (round-12 inner loop) ----
        int ks = __builtin_amdgcn_readfirstlane(offsets[node]);
        int ke = __builtin_amdgcn_readfirstlane(offsets[node + 1]);
        u32 sv = *(const u32*)(px + ((size_t)node << 8));   // self
        float a0 = lo16(sv), a1 = hi16(sv);
        int nb = (ke - ks) >> 3;
        uint4 I = make_uint4(0u, 0u, 0u, 0u);
        if (nb > 0) I = *(const uint4*)(elist + ks);
        int k = ks;
        for (int bb = 0; bb < nb; ++bb) {
            uint4 In = I;
            if (bb + 1 < nb) In = *(const uint4*)(elist + k + 8);  // prefetch
            u32 s0 = I.x & 0xffffu, s1 = I.x >> 16;
            u32 s2 = I.y & 0xffffu, s3 = I.y >> 16;
            u32 s4 = I.z & 0xffffu, s5 = I.z >> 16;
            u32 s6 = I.w & 0xffffu, s7 = I.w >> 16;
            u32 v0 = *(const u32*)(px + ((size_t)s0 << 8));
            u32 v1 = *(const u32*)(px + ((size_t)s1 << 8));
            u32 v2 = *(const u32*)(px + ((size_t)s2 << 8));
            u32 v3 = *(const u32*)(px + ((size_t)s3 << 8));
            u32 v4 = *(const u32*)(px + ((size_t)s4 << 8));
            u32 v5 = *(const u32*)(px + ((size_t)s5 << 8));
            u32 v6 = *(const u32*)(px + ((size_t)s6 << 8));
            u32 v7 = *(const u32*)(px + ((size_t)s7 << 8));
            asm volatile("" ::
                "v"(v0), "v"(v1), "v"(v2), "v"(v3),
                "v"(v4), "v"(v5), "v"(v6), "v"(v7));
            a0 += lo16(v0); a1 += hi16(v0);
            a0 += lo16(v1); a1 += hi16(v1);
            a0 += lo16(v2); a1 += hi16(v2);
            a0 += lo16(v3); a1 += hi16(v3);
            a0 += lo16(v4); a1 += hi16(v4);
            a0 += lo16(v5); a1 += hi16(v5);
            a0 += lo16(v6); a1 += hi16(v6);
            a0 += lo16(v7); a1 += hi16(v7);
            I = In; k += 8;
        }
        lf[buf * 576 + wword] = (u32)f2bf(a0) | ((u32)f2bf(a1) << 16);
        __syncthreads();   // all 8 valid rows of this buf written

        // ---- A-frags from LDS (verified round-6 lane mapping) ----
        const u32* lp = lf + buf * 576 + lr * 36 + (lk << 2);
        s16x8 av0 = *(const s16x8*)(lp);
        s16x8 av1 = *(const s16x8*)(lp + 16);

        f32x4 acc = (f32x4){bia, bia, bia, bia};
        acc = __builtin_amdgcn_mfma_f32_16x16x32_bf16(av0, bf0, acc, 0, 0, 0);
        acc = __builtin_amdgcn_mfma_f32_16x16x32_bf16(av1, bf1, acc, 0, 0, 0);

        // ---- epilogue: this block's 2 valid rows per lane ----
        int R0 = tl * 16 + (lk << 2) + rsel;
        if (out_bf) {
            out_bf[(size_t)R0 * 64 + w * 16 + lr]       = f2bf(acc[rsel]);
            out_bf[(size_t)(R0 + 1) * 64 + w * 16 + lr] = f2bf(acc[rsel + 1]);
        }
        if (out_f32) {
            int n0 = R0 >> 2, b0 = R0 & 3;
            out_f32[(((size_t)b0 * n_nodes + n0) << 6) + w * 16 + lr] = acc[rsel];
            int R1 = R0 + 1;
            int n1 = R1 >> 2, b1 = R1 & 3;
            out_f32[(((size_t)b1 * n_nodes + n1) << 6) + w * 16 + lr] = acc[rsel + 1];
        }
    }
}

// ---------------- fallback (atomic path, proven) ----------------

__global__ __launch_bounds__(256) void gin_scatter(
    const float* __restrict__ h, const int* __restrict__ src,
    const int* __restrict__ dst, float* __restrict__ agg,
    int n_edges, int n_nodes)
{
    long long i = (long long)blockIdx.x * blockDim.x + threadIdx.x;
    int e = (int)(i >> 6);
    if (e >= n_edges) return;
    int lane = (int)(i & 63);
    int b  = lane >> 4;
    int c4 = (lane & 15) << 2;
    int s = src[e];
    int d = dst[e];
    const float4 v = *reinterpret_cast<const float4*>(
        h + ((size_t)b * n_nodes + s) * C_DIM + c4);
    float* o = agg + ((size_t)b * n_nodes + d) * C_DIM + c4;
    unsafeAtomicAdd(o + 0, v.x);
    unsafeAtomicAdd(o + 1, v.y);
    unsafeAtomicAdd(o + 2, v.z);
    unsafeAtomicAdd(o + 3, v.w);
}

__global__ __launch_bounds__(256) void gin_mm(
    const float* __restrict__ hin, const float* __restrict__ agg,
    const float* __restrict__ W, const float* __restrict__ bias,
    float* __restrict__ out, int M)
{
    __shared__ float Ws[64][65];
    __shared__ float rows[4][64];
    int tid = threadIdx.x;
    for (int i = tid; i < 64 * 64; i += 256)
        Ws[i >> 6][i & 63] = W[i];
    int rloc = tid >> 6;
    int j    = tid & 63;
    int row  = blockIdx.x * 4 + rloc;
    if (row < M)
        rows[rloc][j] = hin[(size_t)row * C_DIM + j] + agg[(size_t)row * C_DIM + j];
    __syncthreads();
    if (row < M) {
        float acc = bias[j];
#pragma unroll
        for (int k = 0; k < 64; ++k)
            acc += rows[rloc][k] * Ws[j][k];
        out[(size_t)row * C_DIM + j] = acc;
    }
}

// ---------------- launch ----------------

static inline size_t align256(size_t x) { return (x + 255) & ~(size_t)255; }

extern "C" void kernel_launch(void* const* d_in, const int* in_sizes, int n_in,
                              void* d_out, int out_size, void* d_ws, size_t ws_size,
                              hipStream_t stream)
{
    const float* x   = (const float*)d_in[0];
    const int*   ei  = (const int*)d_in[1];
    const float* W1  = (const float*)d_in[2];
    const float* b1  = (const float*)d_in[3];
    const float* W2  = (const float*)d_in[4];
    const float* b2  = (const float*)d_in[5];
    float* out = (float*)d_out;

    const int n_nodes = in_sizes[0] / (B_DIM * C_DIM);
    const int n_edges = in_sizes[1] / 2;
    const int M = B_DIM * n_nodes;
    const size_t elems = (size_t)M * C_DIM;

    const int* src = ei;
    const int* dst = ei + n_edges;
    const int NB = (n_nodes + 255) / 256;

    // elist capacity: every node padded up to +7 entries
    const size_t elist_cap = (size_t)n_edges + 8u * (size_t)n_nodes;

    // ws layout (fast path); both staging buffers carry a sentinel row
    size_t off = 0;
    size_t o_bufA    = off; off = align256(off + (elems + 256) * sizeof(u16));
    size_t o_bufB    = off; off = align256(off + (elems + 256) * sizeof(u16));
    size_t o_counts  = off; off = align256(off + (size_t)n_nodes * sizeof(int));
    size_t o_offsets = off; off = align256(off + (size_t)(n_nodes + 1) * sizeof(int));
    size_t o_cursor  = off; off = align256(off + (size_t)n_nodes * sizeof(int));
    size_t o_part    = off; off = align256(off + 256 * sizeof(int));
    size_t o_elist   = off; off = align256(off + elist_cap * sizeof(u16));
    const size_t need = off;

    const bool fast = (ws_size >= need) && (n_nodes <= 65535) && (NB <= 256) &&
                      ((elems & 7) == 0) && ((n_nodes & 3) == 0);

    dim3 blk(256);

    if (fast) {
        char* ws = (char*)d_ws;
        u16* bufA    = (u16*)(ws + o_bufA);
        u16* bufB    = (u16*)(ws + o_bufB);
        int* counts  = (int*)(ws + o_counts);
        int* offsets = (int*)(ws + o_offsets);
        int* cursor  = (int*)(ws + o_cursor);
        int* partials= (int*)(ws + o_part);
        u16* elist   = (u16*)(ws + o_elist);

        const int cvt_blocks  = (n_nodes * 32 + 255) / 256;
        const int hist_blocks = (n_edges + 255) / 256;
        const int node_blocks = (n_nodes + 255) / 256;
        dim3 grid_pre((unsigned)(cvt_blocks + hist_blocks + 1));
        dim3 grid_n((unsigned)NB);
        dim3 grid_fp((unsigned)(hist_blocks + node_blocks));
        dim3 grid_g(2048);

        hipMemsetAsync(counts, 0, (size_t)n_nodes * sizeof(int), stream);
        k_pre<<<grid_pre, blk, 0, stream>>>(x, bufA, bufB, n_nodes, dst, counts,
                                            n_edges, cvt_blocks, hist_blocks);
        k_part<<<grid_n, blk, 0, stream>>>(counts, partials, n_nodes);
        k_scan1<<<1, blk, 0, stream>>>(partials, NB);
        k_final<<<grid_n, blk, 0, stream>>>(counts, partials, offsets, cursor, n_nodes);
        k_fillp<<<grid_fp, blk, 0, stream>>>(src, dst, cursor, elist, offsets,
                                             counts, n_nodes, n_edges,
                                             hist_blocks, n_nodes);

        // layer 1: bufA -> bufB (bf16), fused gather+mm
        k_gmm2<<<grid_g, blk, 0, stream>>>(bufA, elist, offsets, W1, b1,
                                           nullptr, bufB, n_nodes);
        // layer 2: bufB -> out (f32), fused gather+mm
        k_gmm2<<<grid_g, blk, 0, stream>>>(bufB, elist, offsets, W2, b2,
                                           out, nullptr, n_nodes);
    } else {
        // fallback: atomic path
        float* agg = (float*)d_ws;
        const size_t h_bytes = elems * sizeof(float);
        dim3 grid_sc((unsigned)(((long long)n_edges * 64 + 255) / 256));
        dim3 grid_mm((unsigned)((M + 3) / 4));

        hipMemsetAsync(agg, 0, h_bytes, stream);
        gin_scatter<<<grid_sc, blk, 0, stream>>>(x, src, dst, agg, n_edges, n_nodes);
        gin_mm<<<grid_mm, blk, 0, stream>>>(x, agg, W1, b1, out, M);

        hipMemsetAsync(agg, 0, h_bytes, stream);
        gin_scatter<<<grid_sc, blk, 0, stream>>>(out, src, dst, agg, n_edges, n_nodes);
        gin_mm<<<grid_mm, blk, 0, stream>>>(out, agg, W2, b2, out, M);
    }
}

// Round 14
// 214.288 us; speedup vs baseline: 2.8917x; 1.0009x over previous
//
#include <hip/hip_runtime.h>

#define C_DIM 64
#define B_DIM 4

typedef unsigned short u16;
typedef unsigned int u32;
typedef __attribute__((ext_vector_type(8))) short s16x8;
typedef __attribute__((ext_vector_type(4))) float f32x4;

__device__ __forceinline__ u16 f2bf(float f) {
    union { u32 u; float f; } t; t.f = f;
    u32 u = t.u;
    return (u16)((u + 0x7FFF + ((u >> 16) & 1)) >> 16);  // RNE
}
__device__ __forceinline__ float lo16(u32 u) {
    union { u32 v; float f; } t; t.v = u << 16; return t.f;
}
__device__ __forceinline__ float hi16(u32 u) {
    union { u32 v; float f; } t; t.v = u & 0xffff0000u; return t.f;
}
__device__ __forceinline__ int pad8(int v) { return (v + 7) & ~7; }

// ---- fused: fp32 (B,N,C) -> bf16 (N,B*C) transpose+convert, dst histogram,
//      and zeroing of the sentinel rows of BOTH staging buffers ----
__global__ __launch_bounds__(256) void k_pre(
    const float* __restrict__ in, u16* __restrict__ outb, u16* __restrict__ outb2,
    int n_nodes, const int* __restrict__ dst, int* __restrict__ counts,
    int n_edges, int cvt_blocks, int hist_blocks)
{
    int bid = (int)blockIdx.x;
    if (bid < cvt_blocks) {
        int i = bid * 256 + threadIdx.x;             // [0, n_nodes*32)
        if (i >= n_nodes * 32) return;
        int n = i >> 5;
        int r = i & 31;
        int b = r >> 3, c8 = (r & 7) << 3;
        const float4* p = (const float4*)(in + ((size_t)b * n_nodes + n) * 64 + c8);
        float4 A = p[0], B = p[1];
        ushort4 lo, hi;
        lo.x = f2bf(A.x); lo.y = f2bf(A.y); lo.z = f2bf(A.z); lo.w = f2bf(A.w);
        hi.x = f2bf(B.x); hi.y = f2bf(B.y); hi.z = f2bf(B.z); hi.w = f2bf(B.w);
        ushort4* q = (ushort4*)(outb + (size_t)n * 256 + b * 64 + c8);
        q[0] = lo; q[1] = hi;
    } else if (bid < cvt_blocks + hist_blocks) {
        int e = (bid - cvt_blocks) * 256 + threadIdx.x;
        if (e < n_edges) atomicAdd(&counts[dst[e]], 1);
    } else {
        // zero sentinel rows (node index n_nodes) of both buffers
        outb [(size_t)n_nodes * 256 + threadIdx.x] = 0;
        outb2[(size_t)n_nodes * 256 + threadIdx.x] = 0;
    }
}

// ---------------- padded CSR scan (multi-block, proven) ----------------

__global__ __launch_bounds__(256) void k_part(
    const int* __restrict__ counts, int* __restrict__ partials, int n_nodes)
{
    __shared__ int s[256];
    int i = blockIdx.x * 256 + threadIdx.x;
    int v = (i < n_nodes) ? pad8(counts[i]) : 0;
    s[threadIdx.x] = v;
    __syncthreads();
    for (int d = 128; d > 0; d >>= 1) {
        if (threadIdx.x < d) s[threadIdx.x] += s[threadIdx.x + d];
        __syncthreads();
    }
    if (threadIdx.x == 0) partials[blockIdx.x] = s[0];
}

// k_final with the partials-scan inlined (each block redundantly scans the
// small partials array in LDS and takes its own prefix; saves a launch).
__global__ __launch_bounds__(256) void k_final(
    const int* __restrict__ counts, const int* __restrict__ partials,
    int* __restrict__ offsets, int* __restrict__ cursor, int n_nodes, int nb)
{
    __shared__ int sp[256];
    __shared__ int s[256];
    int tid = threadIdx.x;
    int pv = (tid < nb) ? partials[tid] : 0;
    sp[tid] = pv;
    __syncthreads();
    for (int d = 1; d < 256; d <<= 1) {
        int t = (tid >= d) ? sp[tid - d] : 0;
        __syncthreads();
        sp[tid] += t;
        __syncthreads();
    }
    int base = (blockIdx.x == 0) ? 0 : sp[blockIdx.x - 1];

    int i = blockIdx.x * 256 + tid;
    int v = (i < n_nodes) ? pad8(counts[i]) : 0;
    s[tid] = v;
    __syncthreads();
    for (int d = 1; d < 256; d <<= 1) {
        int t = (tid >= d) ? s[tid - d] : 0;
        __syncthreads();
        s[tid] += t;
        __syncthreads();
    }
    if (i < n_nodes) {
        int off = base + s[tid] - v;
        offsets[i] = off;
        cursor[i] = off;
        if (i == n_nodes - 1) offsets[n_nodes] = off + v;   // padded total
    }
}

// ---- fused: elist fill (first fill_blocks) + sentinel padding (rest) ----
__global__ __launch_bounds__(256) void k_fillp(
    const int* __restrict__ src, const int* __restrict__ dst,
    int* __restrict__ cursor, u16* __restrict__ elist,
    const int* __restrict__ offsets, const int* __restrict__ counts,
    int n_nodes, int n_edges, int fill_blocks, int sentinel)
{
    if ((int)blockIdx.x < fill_blocks) {
        int e = blockIdx.x * 256 + threadIdx.x;
        if (e < n_edges) {
            int pos = atomicAdd(&cursor[dst[e]], 1);
            elist[pos] = (u16)src[e];
        }
    } else {
        int i = (blockIdx.x - fill_blocks) * 256 + threadIdx.x;
        if (i < n_nodes) {
            int e0 = offsets[i] + counts[i];
            int e1 = offsets[i + 1];
            for (int e = e0; e < e1; ++e) elist[e] = (u16)sentinel;
        }
    }
}

// ---- fused half-split gather + cooperative MFMA matmul, 16-deep MLP ----
// Block (tile tl, half h=blockIdx&1): wave w gathers node tl*4+w's h-half
// (batches 2h,2h+1; lane owns 4B = 2 bf16). Steady state processes TWO
// 8-edge batches per iteration: all 16 value loads issued before one
// keep-alive drain. Packed bf16 agg -> double-buffered LDS A-tile -> per-wave
// j-tile MFMAs -> direct output write (round-6 verified mapping).
__global__ __launch_bounds__(256, 8) void k_gmm2(
    const u16* __restrict__ hb, const u16* __restrict__ elist,
    const int* __restrict__ offsets,
    const float* __restrict__ W,       // (64,64) f32 row-major (out,in)
    const float* __restrict__ bias,
    float* __restrict__ out_f32,       // (B,N,C) fp32, nullable
    u16* __restrict__ out_bf,          // (4N,64) bf16, nullable
    int n_nodes)
{
    __shared__ __align__(16) u32 lds[2][16][36];   // [buf][row][packed bf16x2]
    u32* lf = &lds[0][0][0];
    int tid = threadIdx.x;
    int w  = tid >> 6;            // wave = gathered node j AND mfma j-tile
    int l  = tid & 63;
    int lr = l & 15, lk = l >> 4;
    int h  = blockIdx.x & 1;      // batch-half (XCD parity)

    // zero-init LDS once: rows not owned by this block stay 0 forever
    for (int i = tid; i < 2 * 16 * 36; i += 256) lf[i] = 0u;

    // B fragments + bias for j-tile w only
    s16x8 bf0, bf1;
    {
        const float* wp = W + (w * 16 + lr) * 64 + lk * 8;
        s16x8 f0, f1;
#pragma unroll
        for (int e = 0; e < 8; ++e) {
            f0[e] = (short)f2bf(wp[e]);
            f1[e] = (short)f2bf(wp[e + 32]);
        }
        bf0 = f0; bf1 = f1;
    }
    float bia = bias[w * 16 + lr];

    const int NT = n_nodes >> 2;
    const u16* px = hb + (h << 7) + (l << 1);       // half-slice lane base
    int wword = (((w << 2) | (h << 1) | (l >> 5)) * 36) + (l & 31);
    int rsel = h << 1;                               // valid regs: 2h, 2h+1

    __syncthreads();                                 // LDS zero-init visible

    int buf = 0;
    int step = gridDim.x >> 1;
    for (int tl = blockIdx.x >> 1; tl < NT; tl += step, buf ^= 1) {
        int node = tl * 4 + w;
        // ---- gather this node's h-half, 16 loads in flight ----
        int ks = __builtin_amdgcn_readfirstlane(offsets[node]);
        int ke = __builtin_amdgcn_readfirstlane(offsets[node + 1]);
        u32 sv = *(const u32*)(px + ((size_t)node << 8));   // self
        float a0 = lo16(sv), a1 = hi16(sv);
        int nb = (ke - ks) >> 3;
        uint4 I = make_uint4(0u, 0u, 0u, 0u);
        if (nb > 0) I = *(const uint4*)(elist + ks);
        int k = ks;
        int b = 0;
        for (; b + 2 <= nb; b += 2) {
            uint4 I2 = *(const uint4*)(elist + k + 8);
            u32 s0 = I.x & 0xffffu, s1 = I.x >> 16;
            u32 s2 = I.y & 0xffffu, s3 = I.y >> 16;
            u32 s4 = I.z & 0xffffu, s5 = I.z >> 16;
            u32 s6 = I.w & 0xffffu, s7 = I.w >> 16;
            u32 v0 = *(const u32*)(px + ((size_t)s0 << 8));
            u32 v1 = *(const u32*)(px + ((size_t)s1 << 8));
            u32 v2 = *(const u32*)(px + ((size_t)s2 << 8));
            u32 v3 = *(const u32*)(px + ((size_t)s3 << 8));
            u32 v4 = *(const u32*)(px + ((size_t)s4 << 8));
            u32 v5 = *(const u32*)(px + ((size_t)s5 << 8));
            u32 v6 = *(const u32*)(px + ((size_t)s6 << 8));
            u32 v7 = *(const u32*)(px + ((size_t)s7 << 8));
            u32 t0 = I2.x & 0xffffu, t1 = I2.x >> 16;
            u32 t2 = I2.y & 0xffffu, t3 = I2.y >> 16;
            u32 t4 = I2.z & 0xffffu, t5 = I2.z >> 16;
            u32 t6 = I2.w & 0xffffu, t7 = I2.w >> 16;
            u32 w0 = *(const u32*)(px + ((size_t)t0 << 8));
            u32 w1 = *(const u32*)(px + ((size_t)t1 << 8));
            u32 w2 = *(const u32*)(px + ((size_t)t2 << 8));
            u32 w3 = *(const u32*)(px + ((size_t)t3 << 8));
            u32 w4 = *(const u32*)(px + ((size_t)t4 << 8));
            u32 w5 = *(const u32*)(px + ((size_t)t5 << 8));
            u32 w6 = *(const u32*)(px + ((size_t)t6 << 8));
            u32 w7 = *(const u32*)(px + ((size_t)t7 << 8));
            uint4 In = I;
            if (b + 2 < nb) In = *(const uint4*)(elist + k + 16);
            asm volatile("" ::
                "v"(v0), "v"(v1), "v"(v2), "v"(v3),
                "v"(v4), "v"(v5), "v"(v6), "v"(v7),
                "v"(w0), "v"(w1), "v"(w2), "v"(w3),
                "v"(w4), "v"(w5), "v"(w6), "v"(w7));
            a0 += lo16(v0); a1 += hi16(v0);
            a0 += lo16(v1); a1 += hi16(v1);
            a0 += lo16(v2); a1 += hi16(v2);
            a0 += lo16(v3); a1 += hi16(v3);
            a0 += lo16(v4); a1 += hi16(v4);
            a0 += lo16(v5); a1 += hi16(v5);
            a0 += lo16(v6); a1 += hi16(v6);
            a0 += lo16(v7); a1 += hi16(v7);
            a0 += lo16(w0); a1 += hi16(w0);
            a0 += lo16(w1); a1 += hi16(w1);
            a0 += lo16(w2); a1 += hi16(w2);
            a0 += lo16(w3); a1 += hi16(w3);
            a0 += lo16(w4); a1 += hi16(w4);
            a0 += lo16(w5); a1 += hi16(w5);
            a0 += lo16(w6); a1 += hi16(w6);
            a0 += lo16(w7); a1 += hi16(w7);
            I = In; k += 16;
        }
        if (b < nb) {    // single trailing 8-batch
            u32 s0 = I.x & 0xffffu, s1 = I.x >> 16;
            u32 s2 = I.y & 0xffffu, s3 = I.y >> 16;
            u32 s4 = I.z & 0xffffu, s5 = I.z >> 16;
            u32 s6 = I.w & 0xffffu, s7 = I.w >> 16;
            u32 v0 = *(const u32*)(px + ((size_t)s0 << 8));
            u32 v1 = *(const u32*)(px + ((size_t)s1 << 8));
            u32 v2 = *(const u32*)(px + ((size_t)s2 << 8));
            u32 v3 = *(const u32*)(px + ((size_t)s3 << 8));
            u32 v4 = *(const u32*)(px + ((size_t)s4 << 8));
            u32 v5 = *(const u32*)(px + ((size_t)s5 << 8));
            u32 v6 = *(const u32*)(px + ((size_t)s6 << 8));
            u32 v7 = *(const u32*)(px + ((size_t)s7 << 8));
            asm volatile("" ::
                "v"(v0), "v"(v1), "v"(v2), "v"(v3),
                "v"(v4), "v"(v5), "v"(v6), "v"(v7));
            a0 += lo16(v0); a1 += hi16(v0);
            a0 += lo16(v1); a1 += hi16(v1);
            a0 += lo16(v2); a1 += hi16(v2);
            a0 += lo16(v3); a1 += hi16(v3);
            a0 += lo16(v4); a1 += hi16(v4);
            a0 += lo16(v5); a1 += hi16(v5);
            a0 += lo16(v6); a1 += hi16(v6);
            a0 += lo16(v7); a1 += hi16(v7);
        }
        lf[buf * 576 + wword] = (u32)f2bf(a0) | ((u32)f2bf(a1) << 16);
        __syncthreads();   // all 8 valid rows of this buf written

        // ---- A-frags from LDS (verified round-6 lane mapping) ----
        const u32* lp = lf + buf * 576 + lr * 36 + (lk << 2);
        s16x8 av0 = *(const s16x8*)(lp);
        s16x8 av1 = *(const s16x8*)(lp + 16);

        f32x4 acc = (f32x4){bia, bia, bia, bia};
        acc = __builtin_amdgcn_mfma_f32_16x16x32_bf16(av0, bf0, acc, 0, 0, 0);
        acc = __builtin_amdgcn_mfma_f32_16x16x32_bf16(av1, bf1, acc, 0, 0, 0);

        // ---- epilogue: this block's 2 valid rows per lane ----
        int R0 = tl * 16 + (lk << 2) + rsel;
        if (out_bf) {
            out_bf[(size_t)R0 * 64 + w * 16 + lr]       = f2bf(acc[rsel]);
            out_bf[(size_t)(R0 + 1) * 64 + w * 16 + lr] = f2bf(acc[rsel + 1]);
        }
        if (out_f32) {
            int n0 = R0 >> 2, b0 = R0 & 3;
            out_f32[(((size_t)b0 * n_nodes + n0) << 6) + w * 16 + lr] = acc[rsel];
            int R1 = R0 + 1;
            int n1 = R1 >> 2, b1 = R1 & 3;
            out_f32[(((size_t)b1 * n_nodes + n1) << 6) + w * 16 + lr] = acc[rsel + 1];
        }
    }
}

// ---------------- fallback (atomic path, proven) ----------------

__global__ __launch_bounds__(256) void gin_scatter(
    const float* __restrict__ h, const int* __restrict__ src,
    const int* __restrict__ dst, float* __restrict__ agg,
    int n_edges, int n_nodes)
{
    long long i = (long long)blockIdx.x * blockDim.x + threadIdx.x;
    int e = (int)(i >> 6);
    if (e >= n_edges) return;
    int lane = (int)(i & 63);
    int b  = lane >> 4;
    int c4 = (lane & 15) << 2;
    int s = src[e];
    int d = dst[e];
    const float4 v = *reinterpret_cast<const float4*>(
        h + ((size_t)b * n_nodes + s) * C_DIM + c4);
    float* o = agg + ((size_t)b * n_nodes + d) * C_DIM + c4;
    unsafeAtomicAdd(o + 0, v.x);
    unsafeAtomicAdd(o + 1, v.y);
    unsafeAtomicAdd(o + 2, v.z);
    unsafeAtomicAdd(o + 3, v.w);
}

__global__ __launch_bounds__(256) void gin_mm(
    const float* __restrict__ hin, const float* __restrict__ agg,
    const float* __restrict__ W, const float* __restrict__ bias,
    float* __restrict__ out, int M)
{
    __shared__ float Ws[64][65];
    __shared__ float rows[4][64];
    int tid = threadIdx.x;
    for (int i = tid; i < 64 * 64; i += 256)
        Ws[i >> 6][i & 63] = W[i];
    int rloc = tid >> 6;
    int j    = tid & 63;
    int row  = blockIdx.x * 4 + rloc;
    if (row < M)
        rows[rloc][j] = hin[(size_t)row * C_DIM + j] + agg[(size_t)row * C_DIM + j];
    __syncthreads();
    if (row < M) {
        float acc = bias[j];
#pragma unroll
        for (int k = 0; k < 64; ++k)
            acc += rows[rloc][k] * Ws[j][k];
        out[(size_t)row * C_DIM + j] = acc;
    }
}

// ---------------- launch ----------------

static inline size_t align256(size_t x) { return (x + 255) & ~(size_t)255; }

extern "C" void kernel_launch(void* const* d_in, const int* in_sizes, int n_in,
                              void* d_out, int out_size, void* d_ws, size_t ws_size,
                              hipStream_t stream)
{
    const float* x   = (const float*)d_in[0];
    const int*   ei  = (const int*)d_in[1];
    const float* W1  = (const float*)d_in[2];
    const float* b1  = (const float*)d_in[3];
    const float* W2  = (const float*)d_in[4];
    const float* b2  = (const float*)d_in[5];
    float* out = (float*)d_out;

    const int n_nodes = in_sizes[0] / (B_DIM * C_DIM);
    const int n_edges = in_sizes[1] / 2;
    const int M = B_DIM * n_nodes;
    const size_t elems = (size_t)M * C_DIM;

    const int* src = ei;
    const int* dst = ei + n_edges;
    const int NB = (n_nodes + 255) / 256;

    // elist capacity: every node padded up to +7 entries
    const size_t elist_cap = (size_t)n_edges + 8u * (size_t)n_nodes;

    // ws layout (fast path); both staging buffers carry a sentinel row
    size_t off = 0;
    size_t o_bufA    = off; off = align256(off + (elems + 256) * sizeof(u16));
    size_t o_bufB    = off; off = align256(off + (elems + 256) * sizeof(u16));
    size_t o_counts  = off; off = align256(off + (size_t)n_nodes * sizeof(int));
    size_t o_offsets = off; off = align256(off + (size_t)(n_nodes + 1) * sizeof(int));
    size_t o_cursor  = off; off = align256(off + (size_t)n_nodes * sizeof(int));
    size_t o_part    = off; off = align256(off + 256 * sizeof(int));
    size_t o_elist   = off; off = align256(off + elist_cap * sizeof(u16));
    const size_t need = off;

    const bool fast = (ws_size >= need) && (n_nodes <= 65535) && (NB <= 256) &&
                      ((elems & 7) == 0) && ((n_nodes & 3) == 0);

    dim3 blk(256);

    if (fast) {
        char* ws = (char*)d_ws;
        u16* bufA    = (u16*)(ws + o_bufA);
        u16* bufB    = (u16*)(ws + o_bufB);
        int* counts  = (int*)(ws + o_counts);
        int* offsets = (int*)(ws + o_offsets);
        int* cursor  = (int*)(ws + o_cursor);
        int* partials= (int*)(ws + o_part);
        u16* elist   = (u16*)(ws + o_elist);

        const int cvt_blocks  = (n_nodes * 32 + 255) / 256;
        const int hist_blocks = (n_edges + 255) / 256;
        const int node_blocks = (n_nodes + 255) / 256;
        dim3 grid_pre((unsigned)(cvt_blocks + hist_blocks + 1));
        dim3 grid_n((unsigned)NB);
        dim3 grid_fp((unsigned)(hist_blocks + node_blocks));
        dim3 grid_g(2048);

        hipMemsetAsync(counts, 0, (size_t)n_nodes * sizeof(int), stream);
        k_pre<<<grid_pre, blk, 0, stream>>>(x, bufA, bufB, n_nodes, dst, counts,
                                            n_edges, cvt_blocks, hist_blocks);
        k_part<<<grid_n, blk, 0, stream>>>(counts, partials, n_nodes);
        k_final<<<grid_n, blk, 0, stream>>>(counts, partials, offsets, cursor,
                                            n_nodes, NB);
        k_fillp<<<grid_fp, blk, 0, stream>>>(src, dst, cursor, elist, offsets,
                                             counts, n_nodes, n_edges,
                                             hist_blocks, n_nodes);

        // layer 1: bufA -> bufB (bf16), fused gather+mm
        k_gmm2<<<grid_g, blk, 0, stream>>>(bufA, elist, offsets, W1, b1,
                                           nullptr, bufB, n_nodes);
        // layer 2: bufB -> out (f32), fused gather+mm
        k_gmm2<<<grid_g, blk, 0, stream>>>(bufB, elist, offsets, W2, b2,
                                           out, nullptr, n_nodes);
    } else {
        // fallback: atomic path
        float* agg = (float*)d_ws;
        const size_t h_bytes = elems * sizeof(float);
        dim3 grid_sc((unsigned)(((long long)n_edges * 64 + 255) / 256));
        dim3 grid_mm((unsigned)((M + 3) / 4));

        hipMemsetAsync(agg, 0, h_bytes, stream);
        gin_scatter<<<grid_sc, blk, 0, stream>>>(x, src, dst, agg, n_edges, n_nodes);
        gin_mm<<<grid_mm, blk, 0, stream>>>(x, agg, W1, b1, out, M);

        hipMemsetAsync(agg, 0, h_bytes, stream);
        gin_scatter<<<grid_sc, blk, 0, stream>>>(out, src, dst, agg, n_edges, n_nodes);
        gin_mm<<<grid_mm, blk, 0, stream>>>(out, agg, W2, b2, out, M);
    }
}